// Round 8
// baseline (903.429 us; speedup 1.0000x reference)
//
#include <hip/hip_runtime.h>

#define NN 100000
#define NE 1600000
#define HD 128
#define NL 3
#define NC 40

#define NBK 196     // dst buckets (512 nodes each; 196*512 = 100352 >= NN)
#define NPB 512     // nodes per bucket
#define BSH 9       // bucket shift (dst >> 9)
#define CAP 9216    // per-bucket raw edge capacity (mean 8163, +11 sigma)
#define PCAP 13312  // per-bucket padded CSR capacity: 512*8 + CAP = 13312 exact worst case
#define EPB 6400    // edges per bin block (fewer blocks -> 4x less atomic contention)
#define NBINBLK 250 // 250 * 6400 = NE

typedef unsigned int u32;
typedef unsigned short u16;
typedef __attribute__((ext_vector_type(8))) short short8;
typedef __attribute__((ext_vector_type(4))) float f32x4;

__device__ __forceinline__ float b2f(u16 h){
    union{u32 u; float f;} v; v.u = ((u32)h) << 16; return v.f;
}
__device__ __forceinline__ u16 f2b(float f){
    union{float f; u32 u;} v; v.f = f;
    u32 u = v.u;
    u32 r = (u + 0x7FFFu + ((u >> 16) & 1u)) >> 16;
    return (u16)r;
}

// ---------------- weight conversion + all zero-inits (replaces 3 memsets) ----------------
// Wt[l][n][k] = W[l][k][n]  (transposed, bf16)
__global__ void k_conv_w(const float* __restrict__ Ws, u16* __restrict__ wt,
                         int* __restrict__ gcur, float* __restrict__ stats,
                         int* __restrict__ cnts, u16* __restrict__ hwzero){
    int i = blockIdx.x * blockDim.x + threadIdx.x;
    if (i < NBK) gcur[i] = 0;
    if (i < NL * 2 * HD) stats[i] = 0.f;
    if (i < NL) cnts[i] = 0;
    if (i < HD) hwzero[i] = 0;          // zero row NN of hw (CSR pad target)
    if (i >= NL * HD * HD) return;
    int l = i / (HD * HD);
    int r = i % (HD * HD);
    int n = r / HD;
    int k = r % HD;
    wt[i] = f2b(Ws[l * HD * HD + k * HD + n]);
}

// ---------------- x -> bf16 + first head pass: out = b_out + x @ W_out[0:128] ----------------
__launch_bounds__(256)
__global__ void k_convhead(const float* __restrict__ x, const float* __restrict__ wout,
                           const float* __restrict__ bout, float* __restrict__ out,
                           u16* __restrict__ hA){
    __shared__ float wl[HD * NC]; // rows 0..127 of W_out
    __shared__ float bl[NC];
    int tid = threadIdx.x;
    for (int i = tid; i < HD * NC; i += 256) wl[i] = wout[i];
    if (tid < NC) bl[tid] = bout[tid];
    __syncthreads();
    int n = blockIdx.x * 256 + tid;
    if (n >= NN) return;
    f32x4 acc[10];
    #pragma unroll
    for (int q = 0; q < 10; q++) acc[q] = *reinterpret_cast<const f32x4*>(&bl[q * 4]);
    const float* xr = x + (size_t)n * HD;
    #pragma unroll
    for (int k8 = 0; k8 < HD / 8; k8++){
        float4 v0 = reinterpret_cast<const float4*>(xr)[k8 * 2];
        float4 v1 = reinterpret_cast<const float4*>(xr)[k8 * 2 + 1];
        float xs[8] = {v0.x, v0.y, v0.z, v0.w, v1.x, v1.y, v1.z, v1.w};
        uint4 ov;
        u16* po = (u16*)&ov;
        #pragma unroll
        for (int t = 0; t < 8; t++){
            int f = k8 * 8 + t;
            po[t] = f2b(xs[t]);
            const f32x4* wr = reinterpret_cast<const f32x4*>(&wl[f * NC]);
            #pragma unroll
            for (int q = 0; q < 10; q++) acc[q] += xs[t] * wr[q];
        }
        reinterpret_cast<uint4*>(hA + (size_t)n * HD)[k8] = ov;
    }
    float* orw = out + (size_t)n * NC;
    #pragma unroll
    for (int q = 0; q < 10; q++) reinterpret_cast<f32x4*>(orw)[q] = acc[q];
}

// ---------------- pass 1: bin edges by dst bucket, coalesced grouped writes ----------------
__launch_bounds__(256)
__global__ void k_bin(const int* __restrict__ src, const int* __restrict__ dst,
                      int* __restrict__ gcur, uint2* __restrict__ bb){
    __shared__ int hist[NBK];
    __shared__ int lbase[NBK];
    __shared__ int gbase[NBK];
    __shared__ int cur[NBK];
    __shared__ int wsum[4];
    __shared__ uint2 stage[EPB]; // 51.2 KB
    int tid = threadIdx.x;
    int e0 = blockIdx.x * EPB;
    for (int i = tid; i < NBK; i += 256) hist[i] = 0;
    __syncthreads();
    for (int k = tid; k < EPB; k += 256){
        int d = dst[e0 + k];
        atomicAdd(&hist[d >> BSH], 1);
    }
    __syncthreads();
    // parallel exclusive scan of hist[0..NBK)
    {
        int v = (tid < NBK) ? hist[tid] : 0;
        int lane = tid & 63, w = tid >> 6;
        int incl = v;
        #pragma unroll
        for (int dlt = 1; dlt < 64; dlt <<= 1){
            int t = __shfl_up(incl, dlt);
            if (lane >= dlt) incl += t;
        }
        if (lane == 63) wsum[w] = incl;
        __syncthreads();
        if (tid == 0){
            int run = 0;
            #pragma unroll
            for (int j = 0; j < 4; j++){ int t = wsum[j]; wsum[j] = run; run += t; }
        }
        __syncthreads();
        int excl = wsum[w] + incl - v;
        if (tid < NBK){ lbase[tid] = excl; cur[tid] = excl; }
    }
    __syncthreads();
    if (tid < NBK) gbase[tid] = atomicAdd(&gcur[tid], hist[tid]);
    __syncthreads();
    for (int k = tid; k < EPB; k += 256){
        int s = src[e0 + k], d = dst[e0 + k];
        int pos = atomicAdd(&cur[d >> BSH], 1);
        stage[pos] = make_uint2((u32)s, (u32)d);
    }
    __syncthreads();
    for (int k = tid; k < EPB; k += 256){
        uint2 sd = stage[k];
        int b = (int)(sd.y >> BSH);
        int g = gbase[b] + (k - lbase[b]);
        if (g < CAP) bb[(size_t)b * CAP + g] = sd;
    }
}

// ---------------- pass 2: per-bucket padded CSR build, all global I/O coalesced ----------------
// Per node layout: [self, neighbors..., pad(NN)...] length rounded up to multiple of 8.
// offs[n] = start, oend[n] = start + padded-length (true per-node end; avoids bucket-gap).
__launch_bounds__(512)
__global__ void k_csr(const int* __restrict__ gcur, const uint2* __restrict__ bb,
                      int* __restrict__ csr_src, int* __restrict__ offs,
                      int* __restrict__ oend, float* __restrict__ dinv){
    __shared__ int hist[NPB];
    __shared__ int cur[NPB];
    __shared__ int wsum[8];
    __shared__ int totp_s;
    __shared__ int lcsr[PCAP]; // 52 KB
    int tid = threadIdx.x;
    int b = blockIdx.x;
    int cnt_b = gcur[b]; if (cnt_b > CAP) cnt_b = CAP;
    const uint2* eb = bb + (size_t)b * CAP;
    hist[tid] = 0;
    __syncthreads();
    for (int k = tid; k < cnt_b; k += 512)
        atomicAdd(&hist[eb[k].y & (NPB - 1)], 1);
    __syncthreads();
    int cnt = hist[tid];
    int ps = (1 + cnt + 7) & ~7;   // padded slots incl self
    int lane = tid & 63, w = tid >> 6;
    int incl = ps;
    #pragma unroll
    for (int dlt = 1; dlt < 64; dlt <<= 1){
        int t = __shfl_up(incl, dlt);
        if (lane >= dlt) incl += t;
    }
    if (lane == 63) wsum[w] = incl;
    __syncthreads();
    if (tid == 0){
        int run = 0;
        #pragma unroll
        for (int j = 0; j < 8; j++){ int t = wsum[j]; wsum[j] = run; run += t; }
        totp_s = run;
    }
    __syncthreads();
    int excl = wsum[w] + incl - ps;
    int n = b * NPB + tid;
    offs[n] = b * PCAP + excl;
    oend[n] = b * PCAP + excl + ps;
    if (n < NN) dinv[n] = rsqrtf((float)(cnt + 1));
    cur[tid] = excl + 1;           // neighbors start after self slot
    int totp = totp_s;
    __syncthreads();
    for (int k = tid; k < totp; k += 512) lcsr[k] = NN;   // pad -> zero row
    __syncthreads();
    lcsr[excl] = (n < NN) ? n : NN;    // self edge (tail nodes -> zero row)
    __syncthreads();
    for (int k = tid; k < cnt_b; k += 512){
        uint2 sd = eb[k];
        int pos = atomicAdd(&cur[sd.y & (NPB - 1)], 1);
        lcsr[pos] = (int)sd.x;
    }
    __syncthreads();
    for (int k = tid; k < totp; k += 512)
        csr_src[b * PCAP + k] = lcsr[k];
}

// ---------------- dense GEMM: hw = (h @ W) * dinv[row]  (MFMA bf16) ----------------
__launch_bounds__(256)
__global__ void k_gemm(const u16* __restrict__ h, const u16* __restrict__ wt,
                       const float* __restrict__ dinv, u16* __restrict__ out){
    __shared__ u16 wlds[HD * HD]; // 32KB, XOR-swizzled in 16B units
    int tid = threadIdx.x;
    {
        const uint4* g = reinterpret_cast<const uint4*>(wt);
        #pragma unroll
        for (int i = 0; i < 8; i++){
            int lin16 = tid + 256 * i;
            uint4 v = g[lin16];
            int c = lin16 >> 4;
            int addr16 = lin16 ^ (c & 7);
            reinterpret_cast<uint4*>(wlds)[addr16] = v;
        }
    }
    __syncthreads();

    int wv = tid >> 6, lane = tid & 63;
    int row_base = blockIdx.x * 64 + wv * 16;
    int arow = row_base + (lane & 15);
    if (arow >= NN) arow = NN - 1;
    int koff = (lane >> 4) * 8;

    f32x4 acc[8];
    #pragma unroll
    for (int t = 0; t < 8; t++) acc[t] = (f32x4){0.f, 0.f, 0.f, 0.f};

    #pragma unroll
    for (int kk = 0; kk < 4; kk++){
        short8 a = *reinterpret_cast<const short8*>(h + arow * HD + kk * 32 + koff);
        #pragma unroll
        for (int ct = 0; ct < 8; ct++){
            int c = ct * 16 + (lane & 15);
            int addr16 = (c * 16 + kk * 4 + (koff >> 3)) ^ (c & 7);
            short8 b = *reinterpret_cast<const short8*>(wlds + addr16 * 8);
            acc[ct] = __builtin_amdgcn_mfma_f32_16x16x32_bf16(a, b, acc[ct], 0, 0, 0);
        }
    }

    int drow = row_base + (lane >> 4) * 4;
    int dcol = lane & 15;
    float dv[4];
    #pragma unroll
    for (int r = 0; r < 4; r++){
        int rr = drow + r;
        dv[r] = dinv[rr < NN ? rr : NN - 1];
    }
    #pragma unroll
    for (int ct = 0; ct < 8; ct++){
        #pragma unroll
        for (int r = 0; r < 4; r++){
            int rr = drow + r;
            if (rr < NN) out[rr * HD + ct * 16 + dcol] = f2b(acc[ct][r] * dv[r]);
        }
    }
}

// ---------------- aggregation + BN stats + fused BN-prep (last block) ----------------
// wave per 16 contiguous nodes; padded CSR (self + pad included, multiple of 8)
// agg[d] = dinv[d] * sum(rows) + bias; deep-pipelined row gather (R5 structure, 92us)
__launch_bounds__(256)
__global__ void k_agg(const u16* __restrict__ hw, const int* __restrict__ offs,
                      const int* __restrict__ oend, const int* __restrict__ csr_src,
                      const float* __restrict__ dinv, const float* __restrict__ bias,
                      u16* __restrict__ agg, float* __restrict__ sums,
                      const float* __restrict__ gamma, const float* __restrict__ beta,
                      float* __restrict__ bn, int* __restrict__ cnt_done){
    __shared__ float redS[4][HD];
    __shared__ float redQ[4][HD];
    __shared__ int lastflag;
    int tid = threadIdx.x;
    int lane = tid & 63;
    int wv = tid >> 6;
    int f0 = lane * 2;
    float b0 = bias[f0], b1 = bias[f0 + 1];
    float s0 = 0.f, s1 = 0.f, q0 = 0.f, q1 = 0.f;
    int n0 = (blockIdx.x * 4 + wv) * 16;
    const u32* hw32 = reinterpret_cast<const u32*>(hw); // row = 64 u32, lane offset = lane

    for (int k = 0; k < 16; k++){
        int n = n0 + k;
        if (n >= NN) break;
        float a0 = 0.f, a1 = 0.f, c0 = 0.f, c1 = 0.f;
        int e = offs[n], e1 = oend[n];
        int rem = e1 - e;
        while (rem > 0){
            int win = rem < 64 ? rem : 64;
            int idxv = csr_src[e + lane];       // one coalesced load stages up to 64 indices
            int nch = win >> 3;                 // chunks of 8 (win is multiple of 8)
            u32 va[8], vb[8];

            #pragma unroll
            for (int j = 0; j < 8; j++){
                u32 uid = (u32)__builtin_amdgcn_readlane(idxv, j);
                va[j] = hw32[(size_t)(uid << 6) + (u32)lane];
            }
            for (int c = 1; c < nch; c++){
                if (c & 1){
                    #pragma unroll
                    for (int j = 0; j < 8; j++){
                        u32 uid = (u32)__builtin_amdgcn_readlane(idxv, c * 8 + j);
                        vb[j] = hw32[(size_t)(uid << 6) + (u32)lane];
                    }
                    #pragma unroll
                    for (int j = 0; j < 8; j++){
                        union{u32 u; float f;} L, H;
                        L.u = va[j] << 16; H.u = va[j] & 0xFFFF0000u;
                        a0 += L.f; a1 += H.f;
                    }
                } else {
                    #pragma unroll
                    for (int j = 0; j < 8; j++){
                        u32 uid = (u32)__builtin_amdgcn_readlane(idxv, c * 8 + j);
                        va[j] = hw32[(size_t)(uid << 6) + (u32)lane];
                    }
                    #pragma unroll
                    for (int j = 0; j < 8; j++){
                        union{u32 u; float f;} L, H;
                        L.u = vb[j] << 16; H.u = vb[j] & 0xFFFF0000u;
                        c0 += L.f; c1 += H.f;
                    }
                }
            }
            if (nch & 1){
                #pragma unroll
                for (int j = 0; j < 8; j++){
                    union{u32 u; float f;} L, H;
                    L.u = va[j] << 16; H.u = va[j] & 0xFFFF0000u;
                    a0 += L.f; a1 += H.f;
                }
            } else {
                #pragma unroll
                for (int j = 0; j < 8; j++){
                    union{u32 u; float f;} L, H;
                    L.u = vb[j] << 16; H.u = vb[j] & 0xFFFF0000u;
                    c0 += L.f; c1 += H.f;
                }
            }
            e += win; rem -= win;
        }
        float di = dinv[n];
        a0 = (a0 + c0) * di + b0;
        a1 = (a1 + c1) * di + b1;
        u32 o = ((u32)f2b(a1) << 16) | (u32)f2b(a0);
        *reinterpret_cast<u32*>(agg + (size_t)n * HD + f0) = o;
        s0 += a0; s1 += a1; q0 += a0 * a0; q1 += a1 * a1;
    }

    redS[wv][f0] = s0; redS[wv][f0 + 1] = s1;
    redQ[wv][f0] = q0; redQ[wv][f0 + 1] = q1;
    __syncthreads();
    if (tid < HD){
        float ts = redS[0][tid] + redS[1][tid] + redS[2][tid] + redS[3][tid];
        float tq = redQ[0][tid] + redQ[1][tid] + redQ[2][tid] + redQ[3][tid];
        atomicAdd(&sums[tid], ts);
        atomicAdd(&sums[HD + tid], tq);
    }
    // fused BN-prep: last block computes bn[] (replaces k_bnprep dispatch)
    __threadfence();
    __syncthreads();
    if (tid == 0){
        int done = atomicAdd(cnt_done, 1);
        lastflag = (done == (int)gridDim.x - 1);
    }
    __syncthreads();
    if (lastflag && tid < HD){
        float ts = atomicAdd(&sums[tid], 0.0f);        // device-coherent read
        float tq = atomicAdd(&sums[HD + tid], 0.0f);
        float mu = ts / (float)NN;
        float var = tq / (float)NN - mu * mu;
        float inv = rsqrtf(var + 1e-5f);
        float a = gamma[tid] * inv;
        bn[tid] = a;
        bn[HD + tid] = beta[tid] - mu * a;
    }
}

// ---------------- fused BN-apply + head: hA = BN(agg); out += hA @ W_out[row0:row0+128] ----------------
__launch_bounds__(256)
__global__ void k_bnhead(const u16* __restrict__ agg, const float* __restrict__ bn,
                         const float* __restrict__ wout, float* __restrict__ out,
                         u16* __restrict__ hA, int row0){
    __shared__ float wl[HD * NC]; // 20KB
    __shared__ float A[HD];
    __shared__ float C[HD];
    int tid = threadIdx.x;
    for (int i = tid; i < HD * NC; i += 256) wl[i] = wout[row0 * NC + i];
    if (tid < HD){ A[tid] = bn[tid]; C[tid] = bn[HD + tid]; }
    __syncthreads();
    int n = blockIdx.x * 256 + tid;
    if (n >= NN) return;
    float* orw = out + (size_t)n * NC;
    f32x4 acc[10];
    #pragma unroll
    for (int q = 0; q < 10; q++) acc[q] = reinterpret_cast<const f32x4*>(orw)[q];
    #pragma unroll
    for (int k8 = 0; k8 < HD / 8; k8++){
        uint4 v = reinterpret_cast<const uint4*>(agg + (size_t)n * HD)[k8];
        const u16* pv = (const u16*)&v;
        uint4 ov;
        u16* po = (u16*)&ov;
        #pragma unroll
        for (int t = 0; t < 8; t++){
            int f = k8 * 8 + t;
            float xv = b2f(pv[t]) * A[f] + C[f];
            po[t] = f2b(xv);
            const f32x4* wr = reinterpret_cast<const f32x4*>(&wl[f * NC]);
            #pragma unroll
            for (int q = 0; q < 10; q++) acc[q] += xv * wr[q];
        }
        reinterpret_cast<uint4*>(hA + (size_t)n * HD)[k8] = ov;
    }
    #pragma unroll
    for (int q = 0; q < 10; q++) reinterpret_cast<f32x4*>(orw)[q] = acc[q];
}

// ---------------- launch ----------------
extern "C" void kernel_launch(void* const* d_in, const int* in_sizes, int n_in,
                              void* d_out, int out_size, void* d_ws, size_t ws_size,
                              hipStream_t stream){
    const float* x      = (const float*)d_in[0];
    const float* Ws     = (const float*)d_in[1];
    const float* bs     = (const float*)d_in[2];
    const float* gammas = (const float*)d_in[3];
    const float* betas  = (const float*)d_in[4];
    const float* W_out  = (const float*)d_in[5];
    const float* b_out  = (const float*)d_in[6];
    const int*   ei     = (const int*)d_in[7];
    const int* src = ei;
    const int* dst = ei + NE;
    float* out = (float*)d_out;

    char* ws = (char*)d_ws;
    size_t off = 0;
    auto alloc = [&](size_t bytes) -> char* {
        char* p = ws + off;
        off += (bytes + 255) & ~(size_t)255;
        return p;
    };
    u16*   hA       = (u16*)alloc((size_t)NN * HD * 2);
    u16*   hw       = (u16*)alloc((size_t)(NN + 1) * HD * 2);  // +1 zero row for CSR padding
    u16*   aggb     = (u16*)alloc((size_t)NN * HD * 2);        // aliased: bucket buffer pre-loop
    u16*   wt       = (u16*)alloc((size_t)NL * HD * HD * 2);
    float* dinv     = (float*)alloc((size_t)NN * 4);
    int*   offs     = (int*)alloc((size_t)(NBK * NPB) * 4);
    int*   oend     = (int*)alloc((size_t)(NBK * NPB) * 4);
    int*   gcur     = (int*)alloc((size_t)NBK * 4);
    int*   csr_src  = (int*)alloc(((size_t)NBK * PCAP + 256) * 4);
    float* stats    = (float*)alloc((size_t)NL * 2 * HD * 4);
    float* bn       = (float*)alloc((size_t)2 * HD * 4);
    int*   cnts     = (int*)alloc((size_t)NL * 4);

    uint2* bb = (uint2*)aggb; // 196*9216*8 = 14.45 MB <= 25.6 MB; dead before layer loop

    k_conv_w<<<(NL * HD * HD + 255) / 256, 256, 0, stream>>>(Ws, wt, gcur, stats, cnts,
                                                             hw + (size_t)NN * HD);
    k_bin<<<NBINBLK, 256, 0, stream>>>(src, dst, gcur, bb);
    k_csr<<<NBK, 512, 0, stream>>>(gcur, bb, csr_src, offs, oend, dinv);

    k_convhead<<<(NN + 255) / 256, 256, 0, stream>>>(x, W_out, b_out, out, hA);

    for (int l = 0; l < NL; l++){
        k_gemm<<<(NN + 63) / 64, 256, 0, stream>>>(hA, wt + (size_t)l * HD * HD, dinv, hw);
        k_agg<<<(NN + 63) / 64, 256, 0, stream>>>(hw, offs, oend, csr_src, dinv,
                                                  bs + (size_t)l * HD, aggb,
                                                  stats + (size_t)l * 2 * HD,
                                                  gammas + (size_t)l * HD,
                                                  betas + (size_t)l * HD, bn, cnts + l);
        k_bnhead<<<(NN + 255) / 256, 256, 0, stream>>>(aggb, bn, W_out, out, hA,
                                                       HD + l * HD);
    }
}

// Round 9
// 546.849 us; speedup vs baseline: 1.6521x; 1.6521x over previous
//
#include <hip/hip_runtime.h>

#define NN 100000
#define NE 1600000
#define HD 128
#define NL 3
#define NC 40

#define NBK 196     // dst buckets (512 nodes each; 196*512 = 100352 >= NN)
#define NPB 512     // nodes per bucket
#define BSH 9       // bucket shift (dst >> 9)
#define CAP 9216    // per-bucket raw edge capacity (mean 8163, +11 sigma)
#define PCAP 13312  // per-bucket padded CSR capacity: 512*8 + CAP = 13312 exact worst case
#define EPB 6400    // edges per bin block (fewer blocks -> 4x less atomic contention)
#define NBINBLK 250 // 250 * 6400 = NE

typedef unsigned int u32;
typedef unsigned short u16;
typedef __attribute__((ext_vector_type(8))) short short8;
typedef __attribute__((ext_vector_type(4))) float f32x4;

__device__ __forceinline__ float b2f(u16 h){
    union{u32 u; float f;} v; v.u = ((u32)h) << 16; return v.f;
}
__device__ __forceinline__ u16 f2b(float f){
    union{float f; u32 u;} v; v.f = f;
    u32 u = v.u;
    u32 r = (u + 0x7FFFu + ((u >> 16) & 1u)) >> 16;
    return (u16)r;
}

// ---------------- weight conversion + all zero-inits (replaces memsets) ----------------
// Wt[l][n][k] = W[l][k][n]  (transposed, bf16)
__global__ void k_conv_w(const float* __restrict__ Ws, u16* __restrict__ wt,
                         int* __restrict__ gcur, float* __restrict__ stats,
                         u16* __restrict__ hwzero){
    int i = blockIdx.x * blockDim.x + threadIdx.x;
    if (i < NBK) gcur[i] = 0;
    if (i < NL * 2 * HD) stats[i] = 0.f;
    if (i < HD) hwzero[i] = 0;          // zero row NN of hw (CSR pad target)
    if (i >= NL * HD * HD) return;
    int l = i / (HD * HD);
    int r = i % (HD * HD);
    int n = r / HD;
    int k = r % HD;
    wt[i] = f2b(Ws[l * HD * HD + k * HD + n]);
}

// ---------------- x -> bf16 + first head pass: out = b_out + x @ W_out[0:128] ----------------
__launch_bounds__(256)
__global__ void k_convhead(const float* __restrict__ x, const float* __restrict__ wout,
                           const float* __restrict__ bout, float* __restrict__ out,
                           u16* __restrict__ hA){
    __shared__ float wl[HD * NC]; // rows 0..127 of W_out
    __shared__ float bl[NC];
    int tid = threadIdx.x;
    for (int i = tid; i < HD * NC; i += 256) wl[i] = wout[i];
    if (tid < NC) bl[tid] = bout[tid];
    __syncthreads();
    int n = blockIdx.x * 256 + tid;
    if (n >= NN) return;
    f32x4 acc[10];
    #pragma unroll
    for (int q = 0; q < 10; q++) acc[q] = *reinterpret_cast<const f32x4*>(&bl[q * 4]);
    const float* xr = x + (size_t)n * HD;
    #pragma unroll
    for (int k8 = 0; k8 < HD / 8; k8++){
        float4 v0 = reinterpret_cast<const float4*>(xr)[k8 * 2];
        float4 v1 = reinterpret_cast<const float4*>(xr)[k8 * 2 + 1];
        float xs[8] = {v0.x, v0.y, v0.z, v0.w, v1.x, v1.y, v1.z, v1.w};
        uint4 ov;
        u16* po = (u16*)&ov;
        #pragma unroll
        for (int t = 0; t < 8; t++){
            int f = k8 * 8 + t;
            po[t] = f2b(xs[t]);
            const f32x4* wr = reinterpret_cast<const f32x4*>(&wl[f * NC]);
            #pragma unroll
            for (int q = 0; q < 10; q++) acc[q] += xs[t] * wr[q];
        }
        reinterpret_cast<uint4*>(hA + (size_t)n * HD)[k8] = ov;
    }
    float* orw = out + (size_t)n * NC;
    #pragma unroll
    for (int q = 0; q < 10; q++) reinterpret_cast<f32x4*>(orw)[q] = acc[q];
}

// ---------------- pass 1: bin edges by dst bucket, coalesced grouped writes ----------------
__launch_bounds__(256)
__global__ void k_bin(const int* __restrict__ src, const int* __restrict__ dst,
                      int* __restrict__ gcur, uint2* __restrict__ bb){
    __shared__ int hist[NBK];
    __shared__ int lbase[NBK];
    __shared__ int gbase[NBK];
    __shared__ int cur[NBK];
    __shared__ int wsum[4];
    __shared__ uint2 stage[EPB]; // 51.2 KB
    int tid = threadIdx.x;
    int e0 = blockIdx.x * EPB;
    for (int i = tid; i < NBK; i += 256) hist[i] = 0;
    __syncthreads();
    for (int k = tid; k < EPB; k += 256){
        int d = dst[e0 + k];
        atomicAdd(&hist[d >> BSH], 1);
    }
    __syncthreads();
    // parallel exclusive scan of hist[0..NBK)
    {
        int v = (tid < NBK) ? hist[tid] : 0;
        int lane = tid & 63, w = tid >> 6;
        int incl = v;
        #pragma unroll
        for (int dlt = 1; dlt < 64; dlt <<= 1){
            int t = __shfl_up(incl, dlt);
            if (lane >= dlt) incl += t;
        }
        if (lane == 63) wsum[w] = incl;
        __syncthreads();
        if (tid == 0){
            int run = 0;
            #pragma unroll
            for (int j = 0; j < 4; j++){ int t = wsum[j]; wsum[j] = run; run += t; }
        }
        __syncthreads();
        int excl = wsum[w] + incl - v;
        if (tid < NBK){ lbase[tid] = excl; cur[tid] = excl; }
    }
    __syncthreads();
    if (tid < NBK) gbase[tid] = atomicAdd(&gcur[tid], hist[tid]);
    __syncthreads();
    for (int k = tid; k < EPB; k += 256){
        int s = src[e0 + k], d = dst[e0 + k];
        int pos = atomicAdd(&cur[d >> BSH], 1);
        stage[pos] = make_uint2((u32)s, (u32)d);
    }
    __syncthreads();
    for (int k = tid; k < EPB; k += 256){
        uint2 sd = stage[k];
        int b = (int)(sd.y >> BSH);
        int g = gbase[b] + (k - lbase[b]);
        if (g < CAP) bb[(size_t)b * CAP + g] = sd;
    }
}

// ---------------- pass 2: per-bucket padded CSR build, all global I/O coalesced ----------------
// Per node layout: [self, neighbors..., pad(NN)...] length rounded up to multiple of 8.
// offs[n] = start, oend[n] = start + padded-length (true per-node end; avoids bucket-gap).
__launch_bounds__(512)
__global__ void k_csr(const int* __restrict__ gcur, const uint2* __restrict__ bb,
                      int* __restrict__ csr_src, int* __restrict__ offs,
                      int* __restrict__ oend, float* __restrict__ dinv){
    __shared__ int hist[NPB];
    __shared__ int cur[NPB];
    __shared__ int wsum[8];
    __shared__ int totp_s;
    __shared__ int lcsr[PCAP]; // 52 KB
    int tid = threadIdx.x;
    int b = blockIdx.x;
    int cnt_b = gcur[b]; if (cnt_b > CAP) cnt_b = CAP;
    const uint2* eb = bb + (size_t)b * CAP;
    hist[tid] = 0;
    __syncthreads();
    for (int k = tid; k < cnt_b; k += 512)
        atomicAdd(&hist[eb[k].y & (NPB - 1)], 1);
    __syncthreads();
    int cnt = hist[tid];
    int ps = (1 + cnt + 7) & ~7;   // padded slots incl self
    int lane = tid & 63, w = tid >> 6;
    int incl = ps;
    #pragma unroll
    for (int dlt = 1; dlt < 64; dlt <<= 1){
        int t = __shfl_up(incl, dlt);
        if (lane >= dlt) incl += t;
    }
    if (lane == 63) wsum[w] = incl;
    __syncthreads();
    if (tid == 0){
        int run = 0;
        #pragma unroll
        for (int j = 0; j < 8; j++){ int t = wsum[j]; wsum[j] = run; run += t; }
        totp_s = run;
    }
    __syncthreads();
    int excl = wsum[w] + incl - ps;
    int n = b * NPB + tid;
    offs[n] = b * PCAP + excl;
    oend[n] = b * PCAP + excl + ps;
    if (n < NN) dinv[n] = rsqrtf((float)(cnt + 1));
    cur[tid] = excl + 1;           // neighbors start after self slot
    int totp = totp_s;
    __syncthreads();
    for (int k = tid; k < totp; k += 512) lcsr[k] = NN;   // pad -> zero row
    __syncthreads();
    lcsr[excl] = (n < NN) ? n : NN;    // self edge (tail nodes -> zero row)
    __syncthreads();
    for (int k = tid; k < cnt_b; k += 512){
        uint2 sd = eb[k];
        int pos = atomicAdd(&cur[sd.y & (NPB - 1)], 1);
        lcsr[pos] = (int)sd.x;
    }
    __syncthreads();
    for (int k = tid; k < totp; k += 512)
        csr_src[b * PCAP + k] = lcsr[k];
}

// ---------------- dense GEMM: hw = (h @ W) * dinv[row]  (MFMA bf16) ----------------
__launch_bounds__(256)
__global__ void k_gemm(const u16* __restrict__ h, const u16* __restrict__ wt,
                       const float* __restrict__ dinv, u16* __restrict__ out){
    __shared__ u16 wlds[HD * HD]; // 32KB, XOR-swizzled in 16B units
    int tid = threadIdx.x;
    {
        const uint4* g = reinterpret_cast<const uint4*>(wt);
        #pragma unroll
        for (int i = 0; i < 8; i++){
            int lin16 = tid + 256 * i;
            uint4 v = g[lin16];
            int c = lin16 >> 4;
            int addr16 = lin16 ^ (c & 7);
            reinterpret_cast<uint4*>(wlds)[addr16] = v;
        }
    }
    __syncthreads();

    int wv = tid >> 6, lane = tid & 63;
    int row_base = blockIdx.x * 64 + wv * 16;
    int arow = row_base + (lane & 15);
    if (arow >= NN) arow = NN - 1;
    int koff = (lane >> 4) * 8;

    f32x4 acc[8];
    #pragma unroll
    for (int t = 0; t < 8; t++) acc[t] = (f32x4){0.f, 0.f, 0.f, 0.f};

    #pragma unroll
    for (int kk = 0; kk < 4; kk++){
        short8 a = *reinterpret_cast<const short8*>(h + arow * HD + kk * 32 + koff);
        #pragma unroll
        for (int ct = 0; ct < 8; ct++){
            int c = ct * 16 + (lane & 15);
            int addr16 = (c * 16 + kk * 4 + (koff >> 3)) ^ (c & 7);
            short8 b = *reinterpret_cast<const short8*>(wlds + addr16 * 8);
            acc[ct] = __builtin_amdgcn_mfma_f32_16x16x32_bf16(a, b, acc[ct], 0, 0, 0);
        }
    }

    int drow = row_base + (lane >> 4) * 4;
    int dcol = lane & 15;
    float dv[4];
    #pragma unroll
    for (int r = 0; r < 4; r++){
        int rr = drow + r;
        dv[r] = dinv[rr < NN ? rr : NN - 1];
    }
    #pragma unroll
    for (int ct = 0; ct < 8; ct++){
        #pragma unroll
        for (int r = 0; r < 4; r++){
            int rr = drow + r;
            if (rr < NN) out[rr * HD + ct * 16 + dcol] = f2b(acc[ct][r] * dv[r]);
        }
    }
}

// ---------------- aggregation + BN stats ----------------
// wave per 16 contiguous nodes; padded CSR (self + pad included, multiple of 8)
// agg[d] = dinv[d] * sum(rows) + bias; deep-pipelined row gather (R5 structure, 92us)
__launch_bounds__(256)
__global__ void k_agg(const u16* __restrict__ hw, const int* __restrict__ offs,
                      const int* __restrict__ oend, const int* __restrict__ csr_src,
                      const float* __restrict__ dinv, const float* __restrict__ bias,
                      u16* __restrict__ agg, float* __restrict__ sums){
    __shared__ float redS[4][HD];
    __shared__ float redQ[4][HD];
    int tid = threadIdx.x;
    int lane = tid & 63;
    int wv = tid >> 6;
    int f0 = lane * 2;
    float b0 = bias[f0], b1 = bias[f0 + 1];
    float s0 = 0.f, s1 = 0.f, q0 = 0.f, q1 = 0.f;
    int n0 = (blockIdx.x * 4 + wv) * 16;
    const u32* hw32 = reinterpret_cast<const u32*>(hw); // row = 64 u32, lane offset = lane

    for (int k = 0; k < 16; k++){
        int n = n0 + k;
        if (n >= NN) break;
        float a0 = 0.f, a1 = 0.f, c0 = 0.f, c1 = 0.f;
        int e = offs[n], e1 = oend[n];
        int rem = e1 - e;
        while (rem > 0){
            int win = rem < 64 ? rem : 64;
            int idxv = csr_src[e + lane];       // one coalesced load stages up to 64 indices
            int nch = win >> 3;                 // chunks of 8 (win is multiple of 8)
            u32 va[8], vb[8];

            #pragma unroll
            for (int j = 0; j < 8; j++){
                u32 uid = (u32)__builtin_amdgcn_readlane(idxv, j);
                va[j] = hw32[(size_t)(uid << 6) + (u32)lane];
            }
            for (int c = 1; c < nch; c++){
                if (c & 1){
                    #pragma unroll
                    for (int j = 0; j < 8; j++){
                        u32 uid = (u32)__builtin_amdgcn_readlane(idxv, c * 8 + j);
                        vb[j] = hw32[(size_t)(uid << 6) + (u32)lane];
                    }
                    #pragma unroll
                    for (int j = 0; j < 8; j++){
                        union{u32 u; float f;} L, H;
                        L.u = va[j] << 16; H.u = va[j] & 0xFFFF0000u;
                        a0 += L.f; a1 += H.f;
                    }
                } else {
                    #pragma unroll
                    for (int j = 0; j < 8; j++){
                        u32 uid = (u32)__builtin_amdgcn_readlane(idxv, c * 8 + j);
                        va[j] = hw32[(size_t)(uid << 6) + (u32)lane];
                    }
                    #pragma unroll
                    for (int j = 0; j < 8; j++){
                        union{u32 u; float f;} L, H;
                        L.u = vb[j] << 16; H.u = vb[j] & 0xFFFF0000u;
                        c0 += L.f; c1 += H.f;
                    }
                }
            }
            if (nch & 1){
                #pragma unroll
                for (int j = 0; j < 8; j++){
                    union{u32 u; float f;} L, H;
                    L.u = va[j] << 16; H.u = va[j] & 0xFFFF0000u;
                    a0 += L.f; a1 += H.f;
                }
            } else {
                #pragma unroll
                for (int j = 0; j < 8; j++){
                    union{u32 u; float f;} L, H;
                    L.u = vb[j] << 16; H.u = vb[j] & 0xFFFF0000u;
                    c0 += L.f; c1 += H.f;
                }
            }
            e += win; rem -= win;
        }
        float di = dinv[n];
        a0 = (a0 + c0) * di + b0;
        a1 = (a1 + c1) * di + b1;
        u32 o = ((u32)f2b(a1) << 16) | (u32)f2b(a0);
        *reinterpret_cast<u32*>(agg + (size_t)n * HD + f0) = o;
        s0 += a0; s1 += a1; q0 += a0 * a0; q1 += a1 * a1;
    }

    redS[wv][f0] = s0; redS[wv][f0 + 1] = s1;
    redQ[wv][f0] = q0; redQ[wv][f0 + 1] = q1;
    __syncthreads();
    if (tid < HD){
        float ts = redS[0][tid] + redS[1][tid] + redS[2][tid] + redS[3][tid];
        float tq = redQ[0][tid] + redQ[1][tid] + redQ[2][tid] + redQ[3][tid];
        atomicAdd(&sums[tid], ts);
        atomicAdd(&sums[HD + tid], tq);
    }
}

__global__ void k_bnprep(const float* __restrict__ sums, const float* __restrict__ gamma,
                         const float* __restrict__ beta, float* __restrict__ bn){
    int f = threadIdx.x;
    if (f >= HD) return;
    float mu = sums[f] / (float)NN;
    float var = sums[HD + f] / (float)NN - mu * mu;
    float inv = rsqrtf(var + 1e-5f);
    float a = gamma[f] * inv;
    bn[f] = a;
    bn[HD + f] = beta[f] - mu * a;
}

// ---------------- fused BN-apply + head: hA = BN(agg); out += hA @ W_out[row0:row0+128] ----------------
__launch_bounds__(256)
__global__ void k_bnhead(const u16* __restrict__ agg, const float* __restrict__ bn,
                         const float* __restrict__ wout, float* __restrict__ out,
                         u16* __restrict__ hA, int row0){
    __shared__ float wl[HD * NC]; // 20KB
    __shared__ float A[HD];
    __shared__ float C[HD];
    int tid = threadIdx.x;
    for (int i = tid; i < HD * NC; i += 256) wl[i] = wout[row0 * NC + i];
    if (tid < HD){ A[tid] = bn[tid]; C[tid] = bn[HD + tid]; }
    __syncthreads();
    int n = blockIdx.x * 256 + tid;
    if (n >= NN) return;
    float* orw = out + (size_t)n * NC;
    f32x4 acc[10];
    #pragma unroll
    for (int q = 0; q < 10; q++) acc[q] = reinterpret_cast<const f32x4*>(orw)[q];
    #pragma unroll
    for (int k8 = 0; k8 < HD / 8; k8++){
        uint4 v = reinterpret_cast<const uint4*>(agg + (size_t)n * HD)[k8];
        const u16* pv = (const u16*)&v;
        uint4 ov;
        u16* po = (u16*)&ov;
        #pragma unroll
        for (int t = 0; t < 8; t++){
            int f = k8 * 8 + t;
            float xv = b2f(pv[t]) * A[f] + C[f];
            po[t] = f2b(xv);
            const f32x4* wr = reinterpret_cast<const f32x4*>(&wl[f * NC]);
            #pragma unroll
            for (int q = 0; q < 10; q++) acc[q] += xv * wr[q];
        }
        reinterpret_cast<uint4*>(hA + (size_t)n * HD)[k8] = ov;
    }
    #pragma unroll
    for (int q = 0; q < 10; q++) reinterpret_cast<f32x4*>(orw)[q] = acc[q];
}

// ---------------- launch ----------------
extern "C" void kernel_launch(void* const* d_in, const int* in_sizes, int n_in,
                              void* d_out, int out_size, void* d_ws, size_t ws_size,
                              hipStream_t stream){
    const float* x      = (const float*)d_in[0];
    const float* Ws     = (const float*)d_in[1];
    const float* bs     = (const float*)d_in[2];
    const float* gammas = (const float*)d_in[3];
    const float* betas  = (const float*)d_in[4];
    const float* W_out  = (const float*)d_in[5];
    const float* b_out  = (const float*)d_in[6];
    const int*   ei     = (const int*)d_in[7];
    const int* src = ei;
    const int* dst = ei + NE;
    float* out = (float*)d_out;

    char* ws = (char*)d_ws;
    size_t off = 0;
    auto alloc = [&](size_t bytes) -> char* {
        char* p = ws + off;
        off += (bytes + 255) & ~(size_t)255;
        return p;
    };
    u16*   hA       = (u16*)alloc((size_t)NN * HD * 2);
    u16*   hw       = (u16*)alloc((size_t)(NN + 1) * HD * 2);  // +1 zero row for CSR padding
    u16*   aggb     = (u16*)alloc((size_t)NN * HD * 2);        // aliased: bucket buffer pre-loop
    u16*   wt       = (u16*)alloc((size_t)NL * HD * HD * 2);
    float* dinv     = (float*)alloc((size_t)NN * 4);
    int*   offs     = (int*)alloc((size_t)(NBK * NPB) * 4);
    int*   oend     = (int*)alloc((size_t)(NBK * NPB) * 4);
    int*   gcur     = (int*)alloc((size_t)NBK * 4);
    int*   csr_src  = (int*)alloc(((size_t)NBK * PCAP + 256) * 4);
    float* stats    = (float*)alloc((size_t)NL * 2 * HD * 4);
    float* bn       = (float*)alloc((size_t)2 * HD * 4);

    uint2* bb = (uint2*)aggb; // 196*9216*8 = 14.45 MB <= 25.6 MB; dead before layer loop

    k_conv_w<<<(NL * HD * HD + 255) / 256, 256, 0, stream>>>(Ws, wt, gcur, stats,
                                                             hw + (size_t)NN * HD);
    k_bin<<<NBINBLK, 256, 0, stream>>>(src, dst, gcur, bb);
    k_csr<<<NBK, 512, 0, stream>>>(gcur, bb, csr_src, offs, oend, dinv);

    k_convhead<<<(NN + 255) / 256, 256, 0, stream>>>(x, W_out, b_out, out, hA);

    for (int l = 0; l < NL; l++){
        k_gemm<<<(NN + 63) / 64, 256, 0, stream>>>(hA, wt + (size_t)l * HD * HD, dinv, hw);
        k_agg<<<(NN + 63) / 64, 256, 0, stream>>>(hw, offs, oend, csr_src, dinv,
                                                  bs + (size_t)l * HD, aggb,
                                                  stats + (size_t)l * 2 * HD);
        k_bnprep<<<1, 128, 0, stream>>>(stats + (size_t)l * 2 * HD,
                                        gammas + (size_t)l * HD, betas + (size_t)l * HD, bn);
        k_bnhead<<<(NN + 255) / 256, 256, 0, stream>>>(aggb, bn, W_out, out, hA,
                                                       HD + l * HD);
    }
}

// Round 10
// 459.663 us; speedup vs baseline: 1.9654x; 1.1897x over previous
//
#include <hip/hip_runtime.h>

#define NN 100000
#define NE 1600000
#define HD 128
#define NL 3
#define NC 40
#define NCP 48      // padded head cols (multiple of 16)

#define NBK 196     // dst buckets (512 nodes each; 196*512 = 100352 >= NN)
#define NPB 512     // nodes per bucket
#define BSH 9       // bucket shift (dst >> 9)
#define CAP 9216    // per-bucket raw edge capacity (mean 8163, +11 sigma)
#define PCAP 13312  // per-bucket padded CSR capacity: 512*8 + CAP = 13312 exact worst case
#define EPB 6400    // edges per bin block (fewer blocks -> 4x less atomic contention)
#define NBINBLK 250 // 250 * 6400 = NE

typedef unsigned int u32;
typedef unsigned short u16;
typedef __attribute__((ext_vector_type(8))) short short8;
typedef __attribute__((ext_vector_type(4))) float f32x4;

__device__ __forceinline__ float b2f(u16 h){
    union{u32 u; float f;} v; v.u = ((u32)h) << 16; return v.f;
}
__device__ __forceinline__ u16 f2b(float f){
    union{float f; u32 u;} v; v.f = f;
    u32 u = v.u;
    u32 r = (u + 0x7FFFu + ((u >> 16) & 1u)) >> 16;
    return (u16)r;
}

// ---------------- weight conversion + zero-inits ----------------
// Wt[l][n][k] = W[l][k][n] (bf16); woutt[l][n][k] = Wout[HD + l*HD + k][n] (bf16, n<40 else 0)
__global__ void k_conv_w(const float* __restrict__ Ws, u16* __restrict__ wt,
                         int* __restrict__ gcur, float* __restrict__ stats,
                         u16* __restrict__ hwzero, const float* __restrict__ Wout,
                         u16* __restrict__ woutt){
    int i = blockIdx.x * blockDim.x + threadIdx.x;
    if (i < NBK) gcur[i] = 0;
    if (i < NL * 2 * HD) stats[i] = 0.f;
    if (i < HD) hwzero[i] = 0;          // zero row NN of hw (CSR pad target)
    if (i < NL * NCP * HD){
        int l = i / (NCP * HD);
        int r = i % (NCP * HD);
        int n = r / HD;
        int k = r % HD;
        woutt[i] = (n < NC) ? f2b(Wout[(size_t)(HD + l * HD + k) * NC + n]) : (u16)0;
    }
    if (i >= NL * HD * HD) return;
    int l = i / (HD * HD);
    int r = i % (HD * HD);
    int n = r / HD;
    int k = r % HD;
    wt[i] = f2b(Ws[l * HD * HD + k * HD + n]);
}

// ---------------- x -> bf16 + first head pass: out = b_out + x @ W_out[0:128] ----------------
__launch_bounds__(256)
__global__ void k_convhead(const float* __restrict__ x, const float* __restrict__ wout,
                           const float* __restrict__ bout, float* __restrict__ out,
                           u16* __restrict__ hA){
    __shared__ float wl[HD * NC]; // rows 0..127 of W_out
    __shared__ float bl[NC];
    int tid = threadIdx.x;
    for (int i = tid; i < HD * NC; i += 256) wl[i] = wout[i];
    if (tid < NC) bl[tid] = bout[tid];
    __syncthreads();
    int n = blockIdx.x * 256 + tid;
    if (n >= NN) return;
    f32x4 acc[10];
    #pragma unroll
    for (int q = 0; q < 10; q++) acc[q] = *reinterpret_cast<const f32x4*>(&bl[q * 4]);
    const float* xr = x + (size_t)n * HD;
    #pragma unroll
    for (int k8 = 0; k8 < HD / 8; k8++){
        float4 v0 = reinterpret_cast<const float4*>(xr)[k8 * 2];
        float4 v1 = reinterpret_cast<const float4*>(xr)[k8 * 2 + 1];
        float xs[8] = {v0.x, v0.y, v0.z, v0.w, v1.x, v1.y, v1.z, v1.w};
        uint4 ov;
        u16* po = (u16*)&ov;
        #pragma unroll
        for (int t = 0; t < 8; t++){
            int f = k8 * 8 + t;
            po[t] = f2b(xs[t]);
            const f32x4* wr = reinterpret_cast<const f32x4*>(&wl[f * NC]);
            #pragma unroll
            for (int q = 0; q < 10; q++) acc[q] += xs[t] * wr[q];
        }
        reinterpret_cast<uint4*>(hA + (size_t)n * HD)[k8] = ov;
    }
    float* orw = out + (size_t)n * NC;
    #pragma unroll
    for (int q = 0; q < 10; q++) reinterpret_cast<f32x4*>(orw)[q] = acc[q];
}

// ---------------- pass 1: bin edges by dst bucket, coalesced grouped writes ----------------
__launch_bounds__(256)
__global__ void k_bin(const int* __restrict__ src, const int* __restrict__ dst,
                      int* __restrict__ gcur, uint2* __restrict__ bb){
    __shared__ int hist[NBK];
    __shared__ int lbase[NBK];
    __shared__ int gbase[NBK];
    __shared__ int cur[NBK];
    __shared__ int wsum[4];
    __shared__ uint2 stage[EPB]; // 51.2 KB
    int tid = threadIdx.x;
    int e0 = blockIdx.x * EPB;
    for (int i = tid; i < NBK; i += 256) hist[i] = 0;
    __syncthreads();
    for (int k = tid; k < EPB; k += 256){
        int d = dst[e0 + k];
        atomicAdd(&hist[d >> BSH], 1);
    }
    __syncthreads();
    // parallel exclusive scan of hist[0..NBK)
    {
        int v = (tid < NBK) ? hist[tid] : 0;
        int lane = tid & 63, w = tid >> 6;
        int incl = v;
        #pragma unroll
        for (int dlt = 1; dlt < 64; dlt <<= 1){
            int t = __shfl_up(incl, dlt);
            if (lane >= dlt) incl += t;
        }
        if (lane == 63) wsum[w] = incl;
        __syncthreads();
        if (tid == 0){
            int run = 0;
            #pragma unroll
            for (int j = 0; j < 4; j++){ int t = wsum[j]; wsum[j] = run; run += t; }
        }
        __syncthreads();
        int excl = wsum[w] + incl - v;
        if (tid < NBK){ lbase[tid] = excl; cur[tid] = excl; }
    }
    __syncthreads();
    if (tid < NBK) gbase[tid] = atomicAdd(&gcur[tid], hist[tid]);
    __syncthreads();
    for (int k = tid; k < EPB; k += 256){
        int s = src[e0 + k], d = dst[e0 + k];
        int pos = atomicAdd(&cur[d >> BSH], 1);
        stage[pos] = make_uint2((u32)s, (u32)d);
    }
    __syncthreads();
    for (int k = tid; k < EPB; k += 256){
        uint2 sd = stage[k];
        int b = (int)(sd.y >> BSH);
        int g = gbase[b] + (k - lbase[b]);
        if (g < CAP) bb[(size_t)b * CAP + g] = sd;
    }
}

// ---------------- pass 2: per-bucket padded CSR build, all global I/O coalesced ----------------
__launch_bounds__(512)
__global__ void k_csr(const int* __restrict__ gcur, const uint2* __restrict__ bb,
                      int* __restrict__ csr_src, int* __restrict__ offs,
                      int* __restrict__ oend, float* __restrict__ dinv){
    __shared__ int hist[NPB];
    __shared__ int cur[NPB];
    __shared__ int wsum[8];
    __shared__ int totp_s;
    __shared__ int lcsr[PCAP]; // 52 KB
    int tid = threadIdx.x;
    int b = blockIdx.x;
    int cnt_b = gcur[b]; if (cnt_b > CAP) cnt_b = CAP;
    const uint2* eb = bb + (size_t)b * CAP;
    hist[tid] = 0;
    __syncthreads();
    for (int k = tid; k < cnt_b; k += 512)
        atomicAdd(&hist[eb[k].y & (NPB - 1)], 1);
    __syncthreads();
    int cnt = hist[tid];
    int ps = (1 + cnt + 7) & ~7;   // padded slots incl self
    int lane = tid & 63, w = tid >> 6;
    int incl = ps;
    #pragma unroll
    for (int dlt = 1; dlt < 64; dlt <<= 1){
        int t = __shfl_up(incl, dlt);
        if (lane >= dlt) incl += t;
    }
    if (lane == 63) wsum[w] = incl;
    __syncthreads();
    if (tid == 0){
        int run = 0;
        #pragma unroll
        for (int j = 0; j < 8; j++){ int t = wsum[j]; wsum[j] = run; run += t; }
        totp_s = run;
    }
    __syncthreads();
    int excl = wsum[w] + incl - ps;
    int n = b * NPB + tid;
    offs[n] = b * PCAP + excl;
    oend[n] = b * PCAP + excl + ps;
    if (n < NN) dinv[n] = rsqrtf((float)(cnt + 1));
    cur[tid] = excl + 1;           // neighbors start after self slot
    int totp = totp_s;
    __syncthreads();
    for (int k = tid; k < totp; k += 512) lcsr[k] = NN;   // pad -> zero row
    __syncthreads();
    lcsr[excl] = (n < NN) ? n : NN;    // self edge (tail nodes -> zero row)
    __syncthreads();
    for (int k = tid; k < cnt_b; k += 512){
        uint2 sd = eb[k];
        int pos = atomicAdd(&cur[sd.y & (NPB - 1)], 1);
        lcsr[pos] = (int)sd.x;
    }
    __syncthreads();
    for (int k = tid; k < totp; k += 512)
        csr_src[b * PCAP + k] = lcsr[k];
}

// ---------------- dense GEMM: hw = (h @ W) * dinv[row]  (MFMA bf16) ----------------
__launch_bounds__(256)
__global__ void k_gemm(const u16* __restrict__ h, const u16* __restrict__ wt,
                       const float* __restrict__ dinv, u16* __restrict__ out){
    __shared__ u16 wlds[HD * HD]; // 32KB, XOR-swizzled in 16B units
    int tid = threadIdx.x;
    {
        const uint4* g = reinterpret_cast<const uint4*>(wt);
        #pragma unroll
        for (int i = 0; i < 8; i++){
            int lin16 = tid + 256 * i;
            uint4 v = g[lin16];
            int c = lin16 >> 4;
            int addr16 = lin16 ^ (c & 7);
            reinterpret_cast<uint4*>(wlds)[addr16] = v;
        }
    }
    __syncthreads();

    int wv = tid >> 6, lane = tid & 63;
    int row_base = blockIdx.x * 64 + wv * 16;
    int arow = row_base + (lane & 15);
    if (arow >= NN) arow = NN - 1;
    int koff = (lane >> 4) * 8;

    f32x4 acc[8];
    #pragma unroll
    for (int t = 0; t < 8; t++) acc[t] = (f32x4){0.f, 0.f, 0.f, 0.f};

    #pragma unroll
    for (int kk = 0; kk < 4; kk++){
        short8 a = *reinterpret_cast<const short8*>(h + arow * HD + kk * 32 + koff);
        #pragma unroll
        for (int ct = 0; ct < 8; ct++){
            int c = ct * 16 + (lane & 15);
            int addr16 = (c * 16 + kk * 4 + (koff >> 3)) ^ (c & 7);
            short8 b = *reinterpret_cast<const short8*>(wlds + addr16 * 8);
            acc[ct] = __builtin_amdgcn_mfma_f32_16x16x32_bf16(a, b, acc[ct], 0, 0, 0);
        }
    }

    int drow = row_base + (lane >> 4) * 4;
    int dcol = lane & 15;
    float dv[4];
    #pragma unroll
    for (int r = 0; r < 4; r++){
        int rr = drow + r;
        dv[r] = dinv[rr < NN ? rr : NN - 1];
    }
    #pragma unroll
    for (int ct = 0; ct < 8; ct++){
        #pragma unroll
        for (int r = 0; r < 4; r++){
            int rr = drow + r;
            if (rr < NN) out[rr * HD + ct * 16 + dcol] = f2b(acc[ct][r] * dv[r]);
        }
    }
}

// ---------------- fused BN + layer-GEMM + head-GEMM (MFMA) ----------------
// h = BN(agg) in-register; if DO_HW: hw = (h@W)*dinv; always: out += h @ WoutSlice
template<bool DO_HW>
__launch_bounds__(256)
__global__ void k_gemmbn(const u16* __restrict__ agg, const float* __restrict__ bn,
                         const u16* __restrict__ wt, const u16* __restrict__ woutt,
                         const float* __restrict__ dinv, u16* __restrict__ hw,
                         float* __restrict__ out){
    __shared__ u16 wlds[HD * HD];   // 32 KB (layer weight, swizzled)
    __shared__ u16 wolds[NCP * HD]; // 12 KB (head weight slice, swizzled)
    __shared__ float Al[HD];
    __shared__ float Cl[HD];
    int tid = threadIdx.x;
    if (DO_HW){
        const uint4* g = reinterpret_cast<const uint4*>(wt);
        #pragma unroll
        for (int i = 0; i < 8; i++){
            int lin16 = tid + 256 * i;
            uint4 v = g[lin16];
            int c = lin16 >> 4;
            int addr16 = lin16 ^ (c & 7);
            reinterpret_cast<uint4*>(wlds)[addr16] = v;
        }
    }
    {
        const uint4* g = reinterpret_cast<const uint4*>(woutt);
        #pragma unroll
        for (int i = 0; i < 3; i++){
            int lin16 = tid + 256 * i;   // 0..767 = NCP*16
            uint4 v = g[lin16];
            int c = lin16 >> 4;
            int addr16 = lin16 ^ (c & 7);
            reinterpret_cast<uint4*>(wolds)[addr16] = v;
        }
    }
    if (tid < HD){ Al[tid] = bn[tid]; Cl[tid] = bn[HD + tid]; }
    __syncthreads();

    int wv = tid >> 6, lane = tid & 63;
    int row_base = blockIdx.x * 64 + wv * 16;
    int arow = row_base + (lane & 15);
    if (arow >= NN) arow = NN - 1;
    int koff = (lane >> 4) * 8;

    f32x4 accW[8];
    f32x4 accH[3];
    #pragma unroll
    for (int t = 0; t < 8; t++) accW[t] = (f32x4){0.f, 0.f, 0.f, 0.f};
    #pragma unroll
    for (int t = 0; t < 3; t++) accH[t] = (f32x4){0.f, 0.f, 0.f, 0.f};

    #pragma unroll
    for (int kk = 0; kk < 4; kk++){
        int fb = kk * 32 + koff;
        short8 raw = *reinterpret_cast<const short8*>(agg + (size_t)arow * HD + fb);
        f32x4 A0 = *reinterpret_cast<const f32x4*>(&Al[fb]);
        f32x4 A1 = *reinterpret_cast<const f32x4*>(&Al[fb + 4]);
        f32x4 C0 = *reinterpret_cast<const f32x4*>(&Cl[fb]);
        f32x4 C1 = *reinterpret_cast<const f32x4*>(&Cl[fb + 4]);
        short8 a;
        #pragma unroll
        for (int j = 0; j < 4; j++){
            a[j]     = (short)f2b(b2f((u16)raw[j])     * A0[j] + C0[j]);
            a[j + 4] = (short)f2b(b2f((u16)raw[j + 4]) * A1[j] + C1[j]);
        }
        if (DO_HW){
            #pragma unroll
            for (int ct = 0; ct < 8; ct++){
                int c = ct * 16 + (lane & 15);
                int addr16 = (c * 16 + kk * 4 + (koff >> 3)) ^ (c & 7);
                short8 b = *reinterpret_cast<const short8*>(wlds + addr16 * 8);
                accW[ct] = __builtin_amdgcn_mfma_f32_16x16x32_bf16(a, b, accW[ct], 0, 0, 0);
            }
        }
        #pragma unroll
        for (int ht = 0; ht < 3; ht++){
            int c = ht * 16 + (lane & 15);
            int addr16 = (c * 16 + kk * 4 + (koff >> 3)) ^ (c & 7);
            short8 b = *reinterpret_cast<const short8*>(wolds + addr16 * 8);
            accH[ht] = __builtin_amdgcn_mfma_f32_16x16x32_bf16(a, b, accH[ht], 0, 0, 0);
        }
    }

    int drow = row_base + (lane >> 4) * 4;
    int dcol = lane & 15;
    if (DO_HW){
        float dv[4];
        #pragma unroll
        for (int r = 0; r < 4; r++){
            int rr = drow + r;
            dv[r] = dinv[rr < NN ? rr : NN - 1];
        }
        #pragma unroll
        for (int ct = 0; ct < 8; ct++){
            #pragma unroll
            for (int r = 0; r < 4; r++){
                int rr = drow + r;
                if (rr < NN) hw[rr * HD + ct * 16 + dcol] = f2b(accW[ct][r] * dv[r]);
            }
        }
    }
    #pragma unroll
    for (int ht = 0; ht < 3; ht++){
        int col = ht * 16 + dcol;
        if (col < NC){
            #pragma unroll
            for (int r = 0; r < 4; r++){
                int rr = drow + r;
                if (rr < NN) out[(size_t)rr * NC + col] += accH[ht][r];
            }
        }
    }
}

// ---------------- aggregation + BN stats ----------------
// wave per 16 contiguous nodes; padded CSR; deep-pipelined row gather (R5 structure)
__launch_bounds__(256)
__global__ void k_agg(const u16* __restrict__ hw, const int* __restrict__ offs,
                      const int* __restrict__ oend, const int* __restrict__ csr_src,
                      const float* __restrict__ dinv, const float* __restrict__ bias,
                      u16* __restrict__ agg, float* __restrict__ sums){
    __shared__ float redS[4][HD];
    __shared__ float redQ[4][HD];
    int tid = threadIdx.x;
    int lane = tid & 63;
    int wv = tid >> 6;
    int f0 = lane * 2;
    float b0 = bias[f0], b1 = bias[f0 + 1];
    float s0 = 0.f, s1 = 0.f, q0 = 0.f, q1 = 0.f;
    int n0 = (blockIdx.x * 4 + wv) * 16;
    const u32* hw32 = reinterpret_cast<const u32*>(hw); // row = 64 u32, lane offset = lane

    for (int k = 0; k < 16; k++){
        int n = n0 + k;
        if (n >= NN) break;
        float a0 = 0.f, a1 = 0.f, c0 = 0.f, c1 = 0.f;
        int e = offs[n], e1 = oend[n];
        int rem = e1 - e;
        while (rem > 0){
            int win = rem < 64 ? rem : 64;
            int idxv = csr_src[e + lane];       // one coalesced load stages up to 64 indices
            int nch = win >> 3;                 // chunks of 8 (win is multiple of 8)
            u32 va[8], vb[8];

            #pragma unroll
            for (int j = 0; j < 8; j++){
                u32 uid = (u32)__builtin_amdgcn_readlane(idxv, j);
                va[j] = hw32[(size_t)(uid << 6) + (u32)lane];
            }
            for (int c = 1; c < nch; c++){
                if (c & 1){
                    #pragma unroll
                    for (int j = 0; j < 8; j++){
                        u32 uid = (u32)__builtin_amdgcn_readlane(idxv, c * 8 + j);
                        vb[j] = hw32[(size_t)(uid << 6) + (u32)lane];
                    }
                    #pragma unroll
                    for (int j = 0; j < 8; j++){
                        union{u32 u; float f;} L, H;
                        L.u = va[j] << 16; H.u = va[j] & 0xFFFF0000u;
                        a0 += L.f; a1 += H.f;
                    }
                } else {
                    #pragma unroll
                    for (int j = 0; j < 8; j++){
                        u32 uid = (u32)__builtin_amdgcn_readlane(idxv, c * 8 + j);
                        va[j] = hw32[(size_t)(uid << 6) + (u32)lane];
                    }
                    #pragma unroll
                    for (int j = 0; j < 8; j++){
                        union{u32 u; float f;} L, H;
                        L.u = vb[j] << 16; H.u = vb[j] & 0xFFFF0000u;
                        c0 += L.f; c1 += H.f;
                    }
                }
            }
            if (nch & 1){
                #pragma unroll
                for (int j = 0; j < 8; j++){
                    union{u32 u; float f;} L, H;
                    L.u = va[j] << 16; H.u = va[j] & 0xFFFF0000u;
                    a0 += L.f; a1 += H.f;
                }
            } else {
                #pragma unroll
                for (int j = 0; j < 8; j++){
                    union{u32 u; float f;} L, H;
                    L.u = vb[j] << 16; H.u = vb[j] & 0xFFFF0000u;
                    c0 += L.f; c1 += H.f;
                }
            }
            e += win; rem -= win;
        }
        float di = dinv[n];
        a0 = (a0 + c0) * di + b0;
        a1 = (a1 + c1) * di + b1;
        u32 o = ((u32)f2b(a1) << 16) | (u32)f2b(a0);
        *reinterpret_cast<u32*>(agg + (size_t)n * HD + f0) = o;
        s0 += a0; s1 += a1; q0 += a0 * a0; q1 += a1 * a1;
    }

    redS[wv][f0] = s0; redS[wv][f0 + 1] = s1;
    redQ[wv][f0] = q0; redQ[wv][f0 + 1] = q1;
    __syncthreads();
    if (tid < HD){
        float ts = redS[0][tid] + redS[1][tid] + redS[2][tid] + redS[3][tid];
        float tq = redQ[0][tid] + redQ[1][tid] + redQ[2][tid] + redQ[3][tid];
        atomicAdd(&sums[tid], ts);
        atomicAdd(&sums[HD + tid], tq);
    }
}

__global__ void k_bnprep(const float* __restrict__ sums, const float* __restrict__ gamma,
                         const float* __restrict__ beta, float* __restrict__ bn){
    int f = threadIdx.x;
    if (f >= HD) return;
    float mu = sums[f] / (float)NN;
    float var = sums[HD + f] / (float)NN - mu * mu;
    float inv = rsqrtf(var + 1e-5f);
    float a = gamma[f] * inv;
    bn[f] = a;
    bn[HD + f] = beta[f] - mu * a;
}

// ---------------- launch ----------------
extern "C" void kernel_launch(void* const* d_in, const int* in_sizes, int n_in,
                              void* d_out, int out_size, void* d_ws, size_t ws_size,
                              hipStream_t stream){
    const float* x      = (const float*)d_in[0];
    const float* Ws     = (const float*)d_in[1];
    const float* bs     = (const float*)d_in[2];
    const float* gammas = (const float*)d_in[3];
    const float* betas  = (const float*)d_in[4];
    const float* W_out  = (const float*)d_in[5];
    const float* b_out  = (const float*)d_in[6];
    const int*   ei     = (const int*)d_in[7];
    const int* src = ei;
    const int* dst = ei + NE;
    float* out = (float*)d_out;

    char* ws = (char*)d_ws;
    size_t off = 0;
    auto alloc = [&](size_t bytes) -> char* {
        char* p = ws + off;
        off += (bytes + 255) & ~(size_t)255;
        return p;
    };
    u16*   hA       = (u16*)alloc((size_t)NN * HD * 2);
    u16*   hw       = (u16*)alloc((size_t)(NN + 1) * HD * 2);  // +1 zero row for CSR padding
    u16*   aggb     = (u16*)alloc((size_t)NN * HD * 2);        // aliased: bucket buffer pre-loop
    u16*   wt       = (u16*)alloc((size_t)NL * HD * HD * 2);
    u16*   woutt    = (u16*)alloc((size_t)NL * NCP * HD * 2);
    float* dinv     = (float*)alloc((size_t)NN * 4);
    int*   offs     = (int*)alloc((size_t)(NBK * NPB) * 4);
    int*   oend     = (int*)alloc((size_t)(NBK * NPB) * 4);
    int*   gcur     = (int*)alloc((size_t)NBK * 4);
    int*   csr_src  = (int*)alloc(((size_t)NBK * PCAP + 256) * 4);
    float* stats    = (float*)alloc((size_t)NL * 2 * HD * 4);
    float* bn       = (float*)alloc((size_t)2 * HD * 4);

    uint2* bb = (uint2*)aggb; // 196*9216*8 = 14.45 MB <= 25.6 MB; dead before layer loop

    k_conv_w<<<(NL * HD * HD + 255) / 256, 256, 0, stream>>>(Ws, wt, gcur, stats,
                                                             hw + (size_t)NN * HD,
                                                             W_out, woutt);
    k_bin<<<NBINBLK, 256, 0, stream>>>(src, dst, gcur, bb);
    k_csr<<<NBK, 512, 0, stream>>>(gcur, bb, csr_src, offs, oend, dinv);

    k_convhead<<<(NN + 255) / 256, 256, 0, stream>>>(x, W_out, b_out, out, hA);

    k_gemm<<<(NN + 63) / 64, 256, 0, stream>>>(hA, wt, dinv, hw);

    for (int l = 0; l < NL; l++){
        k_agg<<<(NN + 63) / 64, 256, 0, stream>>>(hw, offs, oend, csr_src, dinv,
                                                  bs + (size_t)l * HD, aggb,
                                                  stats + (size_t)l * 2 * HD);
        k_bnprep<<<1, 128, 0, stream>>>(stats + (size_t)l * 2 * HD,
                                        gammas + (size_t)l * HD, betas + (size_t)l * HD, bn);
        if (l < NL - 1){
            k_gemmbn<true><<<(NN + 63) / 64, 256, 0, stream>>>(
                aggb, bn, wt + (size_t)(l + 1) * HD * HD,
                woutt + (size_t)l * NCP * HD, dinv, hw, out);
        } else {
            k_gemmbn<false><<<(NN + 63) / 64, 256, 0, stream>>>(
                aggb, bn, nullptr, woutt + (size_t)l * NCP * HD, dinv, nullptr, out);
        }
    }
}

// Round 11
// 420.595 us; speedup vs baseline: 2.1480x; 1.0929x over previous
//
#include <hip/hip_runtime.h>

#define NN 100000
#define NE 1600000
#define HD 128
#define NL 3
#define NC 40
#define NCP 48      // padded head cols (multiple of 16)

#define NBK 196     // dst buckets (512 nodes each; 196*512 = 100352 >= NN)
#define NPB 512     // nodes per bucket
#define BSH 9       // bucket shift (dst >> 9)
#define CAP 9216    // per-bucket raw edge capacity (mean 8163, +11 sigma)
#define PCAP 13312  // per-bucket padded CSR capacity: 512*8 + CAP = 13312 exact worst case
#define EPB 6400    // edges per bin block
#define NBINBLK 250 // 250 * 6400 = NE

typedef unsigned int u32;
typedef unsigned short u16;
typedef __attribute__((ext_vector_type(8))) short short8;
typedef __attribute__((ext_vector_type(4))) float f32x4;

__device__ __forceinline__ float b2f(u16 h){
    union{u32 u; float f;} v; v.u = ((u32)h) << 16; return v.f;
}
__device__ __forceinline__ u16 f2b(float f){
    union{float f; u32 u;} v; v.f = f;
    u32 u = v.u;
    u32 r = (u + 0x7FFFu + ((u >> 16) & 1u)) >> 16;
    return (u16)r;
}

// ---------------- weight conversion + zero-inits ----------------
// Wt[l][n][k] = W[l][k][n] (bf16)
// woutt[li][n][k] = Wout[li*HD + k][n] (bf16, n<40 else 0), li = 0..NL (4 slices)
__global__ void k_conv_w(const float* __restrict__ Ws, u16* __restrict__ wt,
                         int* __restrict__ gcur, float* __restrict__ stats,
                         u16* __restrict__ hwzero, const float* __restrict__ Wout,
                         u16* __restrict__ woutt){
    int i = blockIdx.x * blockDim.x + threadIdx.x;
    if (i < NBK) gcur[i] = 0;
    if (i < NL * 2 * HD) stats[i] = 0.f;
    if (i < HD) hwzero[i] = 0;          // zero row NN of hw (CSR pad target)
    if (i < (NL + 1) * NCP * HD){
        int li = i / (NCP * HD);
        int r = i % (NCP * HD);
        int n = r / HD;
        int k = r % HD;
        woutt[i] = (n < NC) ? f2b(Wout[(size_t)(li * HD + k) * NC + n]) : (u16)0;
    }
    if (i >= NL * HD * HD) return;
    int l = i / (HD * HD);
    int r = i % (HD * HD);
    int n = r / HD;
    int k = r % HD;
    wt[i] = f2b(Ws[l * HD * HD + k * HD + n]);
}

// ---------------- pass 1: bin edges by dst bucket; packed u32 (src | (d&511)<<17) ----------------
__launch_bounds__(256)
__global__ void k_bin(const int* __restrict__ src, const int* __restrict__ dst,
                      int* __restrict__ gcur, u32* __restrict__ bb){
    __shared__ int hist[NBK];
    __shared__ int lbase[NBK];
    __shared__ int gbase[NBK];
    __shared__ int cur[NBK];
    __shared__ int wsum[4];
    __shared__ uint2 stage[EPB]; // 51.2 KB
    int tid = threadIdx.x;
    int e0 = blockIdx.x * EPB;
    for (int i = tid; i < NBK; i += 256) hist[i] = 0;
    __syncthreads();
    for (int k = tid; k < EPB; k += 256){
        int d = dst[e0 + k];
        atomicAdd(&hist[d >> BSH], 1);
    }
    __syncthreads();
    // parallel exclusive scan of hist[0..NBK)
    {
        int v = (tid < NBK) ? hist[tid] : 0;
        int lane = tid & 63, w = tid >> 6;
        int incl = v;
        #pragma unroll
        for (int dlt = 1; dlt < 64; dlt <<= 1){
            int t = __shfl_up(incl, dlt);
            if (lane >= dlt) incl += t;
        }
        if (lane == 63) wsum[w] = incl;
        __syncthreads();
        if (tid == 0){
            int run = 0;
            #pragma unroll
            for (int j = 0; j < 4; j++){ int t = wsum[j]; wsum[j] = run; run += t; }
        }
        __syncthreads();
        int excl = wsum[w] + incl - v;
        if (tid < NBK){ lbase[tid] = excl; cur[tid] = excl; }
    }
    __syncthreads();
    if (tid < NBK) gbase[tid] = atomicAdd(&gcur[tid], hist[tid]);
    __syncthreads();
    for (int k = tid; k < EPB; k += 256){
        int s = src[e0 + k], d = dst[e0 + k];
        int pos = atomicAdd(&cur[d >> BSH], 1);
        stage[pos] = make_uint2((u32)s, (u32)d);
    }
    __syncthreads();
    for (int k = tid; k < EPB; k += 256){
        uint2 sd = stage[k];
        int b = (int)(sd.y >> BSH);
        int g = gbase[b] + (k - lbase[b]);
        if (g < CAP) bb[(size_t)b * CAP + g] = sd.x | ((sd.y & (NPB - 1)) << 17);
    }
}

// ---------------- pass 2: per-bucket padded CSR build, all global I/O coalesced ----------------
__launch_bounds__(512)
__global__ void k_csr(const int* __restrict__ gcur, const u32* __restrict__ bb,
                      int* __restrict__ csr_src, int* __restrict__ offs,
                      int* __restrict__ oend, float* __restrict__ dinv){
    __shared__ int hist[NPB];
    __shared__ int cur[NPB];
    __shared__ int wsum[8];
    __shared__ int totp_s;
    __shared__ int lcsr[PCAP]; // 52 KB
    int tid = threadIdx.x;
    int b = blockIdx.x;
    int cnt_b = gcur[b]; if (cnt_b > CAP) cnt_b = CAP;
    const u32* eb = bb + (size_t)b * CAP;
    hist[tid] = 0;
    __syncthreads();
    for (int k = tid; k < cnt_b; k += 512)
        atomicAdd(&hist[eb[k] >> 17], 1);
    __syncthreads();
    int cnt = hist[tid];
    int ps = (1 + cnt + 7) & ~7;   // padded slots incl self
    int lane = tid & 63, w = tid >> 6;
    int incl = ps;
    #pragma unroll
    for (int dlt = 1; dlt < 64; dlt <<= 1){
        int t = __shfl_up(incl, dlt);
        if (lane >= dlt) incl += t;
    }
    if (lane == 63) wsum[w] = incl;
    __syncthreads();
    if (tid == 0){
        int run = 0;
        #pragma unroll
        for (int j = 0; j < 8; j++){ int t = wsum[j]; wsum[j] = run; run += t; }
        totp_s = run;
    }
    __syncthreads();
    int excl = wsum[w] + incl - ps;
    int n = b * NPB + tid;
    offs[n] = b * PCAP + excl;
    oend[n] = b * PCAP + excl + ps;
    if (n < NN) dinv[n] = rsqrtf((float)(cnt + 1));
    cur[tid] = excl + 1;           // neighbors start after self slot
    int totp = totp_s;
    __syncthreads();
    for (int k = tid; k < totp; k += 512) lcsr[k] = NN;   // pad -> zero row
    __syncthreads();
    lcsr[excl] = (n < NN) ? n : NN;    // self edge (tail nodes -> zero row)
    __syncthreads();
    for (int k = tid; k < cnt_b; k += 512){
        u32 sd = eb[k];
        int pos = atomicAdd(&cur[sd >> 17], 1);
        lcsr[pos] = (int)(sd & 0x1FFFFu);
    }
    __syncthreads();
    for (int k = tid; k < totp; k += 512)
        csr_src[b * PCAP + k] = lcsr[k];
}

// ---------------- fused x->bf16 + layer0 GEMM + head slice 0 (MFMA) ----------------
// hw = (bf16(x) @ W0) * dinv ; out = b_out + bf16(x) @ WoutSlice0
__launch_bounds__(256)
__global__ void k_convgemm(const float* __restrict__ x, const u16* __restrict__ wt,
                           const u16* __restrict__ woutt, const float* __restrict__ bout,
                           const float* __restrict__ dinv, u16* __restrict__ hw,
                           float* __restrict__ out){
    __shared__ u16 wlds[HD * HD];   // 32 KB
    __shared__ u16 wolds[NCP * HD]; // 12 KB
    __shared__ float bl[NC];
    int tid = threadIdx.x;
    {
        const uint4* g = reinterpret_cast<const uint4*>(wt);
        #pragma unroll
        for (int i = 0; i < 8; i++){
            int lin16 = tid + 256 * i;
            uint4 v = g[lin16];
            int c = lin16 >> 4;
            int addr16 = lin16 ^ (c & 7);
            reinterpret_cast<uint4*>(wlds)[addr16] = v;
        }
    }
    {
        const uint4* g = reinterpret_cast<const uint4*>(woutt);
        #pragma unroll
        for (int i = 0; i < 3; i++){
            int lin16 = tid + 256 * i;
            uint4 v = g[lin16];
            int c = lin16 >> 4;
            int addr16 = lin16 ^ (c & 7);
            reinterpret_cast<uint4*>(wolds)[addr16] = v;
        }
    }
    if (tid < NC) bl[tid] = bout[tid];
    __syncthreads();

    int wv = tid >> 6, lane = tid & 63;
    int row_base = blockIdx.x * 64 + wv * 16;
    int arow = row_base + (lane & 15);
    if (arow >= NN) arow = NN - 1;
    int koff = (lane >> 4) * 8;

    f32x4 accW[8];
    f32x4 accH[3];
    #pragma unroll
    for (int t = 0; t < 8; t++) accW[t] = (f32x4){0.f, 0.f, 0.f, 0.f};
    #pragma unroll
    for (int t = 0; t < 3; t++) accH[t] = (f32x4){0.f, 0.f, 0.f, 0.f};

    #pragma unroll
    for (int kk = 0; kk < 4; kk++){
        int fb = kk * 32 + koff;
        const float4* xr = reinterpret_cast<const float4*>(x + (size_t)arow * HD + fb);
        float4 v0 = xr[0];
        float4 v1 = xr[1];
        short8 a;
        a[0] = (short)f2b(v0.x); a[1] = (short)f2b(v0.y);
        a[2] = (short)f2b(v0.z); a[3] = (short)f2b(v0.w);
        a[4] = (short)f2b(v1.x); a[5] = (short)f2b(v1.y);
        a[6] = (short)f2b(v1.z); a[7] = (short)f2b(v1.w);
        #pragma unroll
        for (int ct = 0; ct < 8; ct++){
            int c = ct * 16 + (lane & 15);
            int addr16 = (c * 16 + kk * 4 + (koff >> 3)) ^ (c & 7);
            short8 b = *reinterpret_cast<const short8*>(wlds + addr16 * 8);
            accW[ct] = __builtin_amdgcn_mfma_f32_16x16x32_bf16(a, b, accW[ct], 0, 0, 0);
        }
        #pragma unroll
        for (int ht = 0; ht < 3; ht++){
            int c = ht * 16 + (lane & 15);
            int addr16 = (c * 16 + kk * 4 + (koff >> 3)) ^ (c & 7);
            short8 b = *reinterpret_cast<const short8*>(wolds + addr16 * 8);
            accH[ht] = __builtin_amdgcn_mfma_f32_16x16x32_bf16(a, b, accH[ht], 0, 0, 0);
        }
    }

    int drow = row_base + (lane >> 4) * 4;
    int dcol = lane & 15;
    float dv[4];
    #pragma unroll
    for (int r = 0; r < 4; r++){
        int rr = drow + r;
        dv[r] = dinv[rr < NN ? rr : NN - 1];
    }
    #pragma unroll
    for (int ct = 0; ct < 8; ct++){
        #pragma unroll
        for (int r = 0; r < 4; r++){
            int rr = drow + r;
            if (rr < NN) hw[rr * HD + ct * 16 + dcol] = f2b(accW[ct][r] * dv[r]);
        }
    }
    #pragma unroll
    for (int ht = 0; ht < 3; ht++){
        int col = ht * 16 + dcol;
        if (col < NC){
            float bv = bl[col];
            #pragma unroll
            for (int r = 0; r < 4; r++){
                int rr = drow + r;
                if (rr < NN) out[(size_t)rr * NC + col] = bv + accH[ht][r];
            }
        }
    }
}

// ---------------- fused BN(from sums) + layer-GEMM + head-GEMM (MFMA) ----------------
// h = BN(agg) in-register; if DO_HW: hw = (h@W)*dinv; always: out += h @ WoutSlice
template<bool DO_HW>
__launch_bounds__(256)
__global__ void k_gemmbn(const u16* __restrict__ agg, const float* __restrict__ sums,
                         const float* __restrict__ gamma, const float* __restrict__ beta,
                         const u16* __restrict__ wt, const u16* __restrict__ woutt,
                         const float* __restrict__ dinv, u16* __restrict__ hw,
                         float* __restrict__ out){
    __shared__ u16 wlds[HD * HD];   // 32 KB (layer weight, swizzled)
    __shared__ u16 wolds[NCP * HD]; // 12 KB (head weight slice, swizzled)
    __shared__ float Al[HD];
    __shared__ float Cl[HD];
    int tid = threadIdx.x;
    if (DO_HW){
        const uint4* g = reinterpret_cast<const uint4*>(wt);
        #pragma unroll
        for (int i = 0; i < 8; i++){
            int lin16 = tid + 256 * i;
            uint4 v = g[lin16];
            int c = lin16 >> 4;
            int addr16 = lin16 ^ (c & 7);
            reinterpret_cast<uint4*>(wlds)[addr16] = v;
        }
    }
    {
        const uint4* g = reinterpret_cast<const uint4*>(woutt);
        #pragma unroll
        for (int i = 0; i < 3; i++){
            int lin16 = tid + 256 * i;   // 0..767 = NCP*16
            uint4 v = g[lin16];
            int c = lin16 >> 4;
            int addr16 = lin16 ^ (c & 7);
            reinterpret_cast<uint4*>(wolds)[addr16] = v;
        }
    }
    if (tid < HD){
        float mu = sums[tid] / (float)NN;
        float var = sums[HD + tid] / (float)NN - mu * mu;
        float inv = rsqrtf(var + 1e-5f);
        float a = gamma[tid] * inv;
        Al[tid] = a;
        Cl[tid] = beta[tid] - mu * a;
    }
    __syncthreads();

    int wv = tid >> 6, lane = tid & 63;
    int row_base = blockIdx.x * 64 + wv * 16;
    int arow = row_base + (lane & 15);
    if (arow >= NN) arow = NN - 1;
    int koff = (lane >> 4) * 8;

    f32x4 accW[8];
    f32x4 accH[3];
    #pragma unroll
    for (int t = 0; t < 8; t++) accW[t] = (f32x4){0.f, 0.f, 0.f, 0.f};
    #pragma unroll
    for (int t = 0; t < 3; t++) accH[t] = (f32x4){0.f, 0.f, 0.f, 0.f};

    #pragma unroll
    for (int kk = 0; kk < 4; kk++){
        int fb = kk * 32 + koff;
        short8 raw = *reinterpret_cast<const short8*>(agg + (size_t)arow * HD + fb);
        f32x4 A0 = *reinterpret_cast<const f32x4*>(&Al[fb]);
        f32x4 A1 = *reinterpret_cast<const f32x4*>(&Al[fb + 4]);
        f32x4 C0 = *reinterpret_cast<const f32x4*>(&Cl[fb]);
        f32x4 C1 = *reinterpret_cast<const f32x4*>(&Cl[fb + 4]);
        short8 a;
        #pragma unroll
        for (int j = 0; j < 4; j++){
            a[j]     = (short)f2b(b2f((u16)raw[j])     * A0[j] + C0[j]);
            a[j + 4] = (short)f2b(b2f((u16)raw[j + 4]) * A1[j] + C1[j]);
        }
        if (DO_HW){
            #pragma unroll
            for (int ct = 0; ct < 8; ct++){
                int c = ct * 16 + (lane & 15);
                int addr16 = (c * 16 + kk * 4 + (koff >> 3)) ^ (c & 7);
                short8 b = *reinterpret_cast<const short8*>(wlds + addr16 * 8);
                accW[ct] = __builtin_amdgcn_mfma_f32_16x16x32_bf16(a, b, accW[ct], 0, 0, 0);
            }
        }
        #pragma unroll
        for (int ht = 0; ht < 3; ht++){
            int c = ht * 16 + (lane & 15);
            int addr16 = (c * 16 + kk * 4 + (koff >> 3)) ^ (c & 7);
            short8 b = *reinterpret_cast<const short8*>(wolds + addr16 * 8);
            accH[ht] = __builtin_amdgcn_mfma_f32_16x16x32_bf16(a, b, accH[ht], 0, 0, 0);
        }
    }

    int drow = row_base + (lane >> 4) * 4;
    int dcol = lane & 15;
    if (DO_HW){
        float dv[4];
        #pragma unroll
        for (int r = 0; r < 4; r++){
            int rr = drow + r;
            dv[r] = dinv[rr < NN ? rr : NN - 1];
        }
        #pragma unroll
        for (int ct = 0; ct < 8; ct++){
            #pragma unroll
            for (int r = 0; r < 4; r++){
                int rr = drow + r;
                if (rr < NN) hw[rr * HD + ct * 16 + dcol] = f2b(accW[ct][r] * dv[r]);
            }
        }
    }
    #pragma unroll
    for (int ht = 0; ht < 3; ht++){
        int col = ht * 16 + dcol;
        if (col < NC){
            #pragma unroll
            for (int r = 0; r < 4; r++){
                int rr = drow + r;
                if (rr < NN) out[(size_t)rr * NC + col] += accH[ht][r];
            }
        }
    }
}

// ---------------- aggregation + BN stats ----------------
// wave per 16 contiguous nodes; padded CSR; deep-pipelined row gather (R5 structure)
__launch_bounds__(256)
__global__ void k_agg(const u16* __restrict__ hw, const int* __restrict__ offs,
                      const int* __restrict__ oend, const int* __restrict__ csr_src,
                      const float* __restrict__ dinv, const float* __restrict__ bias,
                      u16* __restrict__ agg, float* __restrict__ sums){
    __shared__ float redS[4][HD];
    __shared__ float redQ[4][HD];
    int tid = threadIdx.x;
    int lane = tid & 63;
    int wv = tid >> 6;
    int f0 = lane * 2;
    float b0 = bias[f0], b1 = bias[f0 + 1];
    float s0 = 0.f, s1 = 0.f, q0 = 0.f, q1 = 0.f;
    int n0 = (blockIdx.x * 4 + wv) * 16;
    const u32* hw32 = reinterpret_cast<const u32*>(hw); // row = 64 u32, lane offset = lane

    for (int k = 0; k < 16; k++){
        int n = n0 + k;
        if (n >= NN) break;
        float a0 = 0.f, a1 = 0.f, c0 = 0.f, c1 = 0.f;
        int e = offs[n], e1 = oend[n];
        int rem = e1 - e;
        while (rem > 0){
            int win = rem < 64 ? rem : 64;
            int idxv = csr_src[e + lane];       // one coalesced load stages up to 64 indices
            int nch = win >> 3;                 // chunks of 8 (win is multiple of 8)
            u32 va[8], vb[8];

            #pragma unroll
            for (int j = 0; j < 8; j++){
                u32 uid = (u32)__builtin_amdgcn_readlane(idxv, j);
                va[j] = hw32[(size_t)(uid << 6) + (u32)lane];
            }
            for (int c = 1; c < nch; c++){
                if (c & 1){
                    #pragma unroll
                    for (int j = 0; j < 8; j++){
                        u32 uid = (u32)__builtin_amdgcn_readlane(idxv, c * 8 + j);
                        vb[j] = hw32[(size_t)(uid << 6) + (u32)lane];
                    }
                    #pragma unroll
                    for (int j = 0; j < 8; j++){
                        union{u32 u; float f;} L, H;
                        L.u = va[j] << 16; H.u = va[j] & 0xFFFF0000u;
                        a0 += L.f; a1 += H.f;
                    }
                } else {
                    #pragma unroll
                    for (int j = 0; j < 8; j++){
                        u32 uid = (u32)__builtin_amdgcn_readlane(idxv, c * 8 + j);
                        va[j] = hw32[(size_t)(uid << 6) + (u32)lane];
                    }
                    #pragma unroll
                    for (int j = 0; j < 8; j++){
                        union{u32 u; float f;} L, H;
                        L.u = vb[j] << 16; H.u = vb[j] & 0xFFFF0000u;
                        c0 += L.f; c1 += H.f;
                    }
                }
            }
            if (nch & 1){
                #pragma unroll
                for (int j = 0; j < 8; j++){
                    union{u32 u; float f;} L, H;
                    L.u = va[j] << 16; H.u = va[j] & 0xFFFF0000u;
                    a0 += L.f; a1 += H.f;
                }
            } else {
                #pragma unroll
                for (int j = 0; j < 8; j++){
                    union{u32 u; float f;} L, H;
                    L.u = vb[j] << 16; H.u = vb[j] & 0xFFFF0000u;
                    c0 += L.f; c1 += H.f;
                }
            }
            e += win; rem -= win;
        }
        float di = dinv[n];
        a0 = (a0 + c0) * di + b0;
        a1 = (a1 + c1) * di + b1;
        u32 o = ((u32)f2b(a1) << 16) | (u32)f2b(a0);
        *reinterpret_cast<u32*>(agg + (size_t)n * HD + f0) = o;
        s0 += a0; s1 += a1; q0 += a0 * a0; q1 += a1 * a1;
    }

    redS[wv][f0] = s0; redS[wv][f0 + 1] = s1;
    redQ[wv][f0] = q0; redQ[wv][f0 + 1] = q1;
    __syncthreads();
    if (tid < HD){
        float ts = redS[0][tid] + redS[1][tid] + redS[2][tid] + redS[3][tid];
        float tq = redQ[0][tid] + redQ[1][tid] + redQ[2][tid] + redQ[3][tid];
        atomicAdd(&sums[tid], ts);
        atomicAdd(&sums[HD + tid], tq);
    }
}

// ---------------- launch ----------------
extern "C" void kernel_launch(void* const* d_in, const int* in_sizes, int n_in,
                              void* d_out, int out_size, void* d_ws, size_t ws_size,
                              hipStream_t stream){
    const float* x      = (const float*)d_in[0];
    const float* Ws     = (const float*)d_in[1];
    const float* bs     = (const float*)d_in[2];
    const float* gammas = (const float*)d_in[3];
    const float* betas  = (const float*)d_in[4];
    const float* W_out  = (const float*)d_in[5];
    const float* b_out  = (const float*)d_in[6];
    const int*   ei     = (const int*)d_in[7];
    const int* src = ei;
    const int* dst = ei + NE;
    float* out = (float*)d_out;

    char* ws = (char*)d_ws;
    size_t off = 0;
    auto alloc = [&](size_t bytes) -> char* {
        char* p = ws + off;
        off += (bytes + 255) & ~(size_t)255;
        return p;
    };
    u16*   hw       = (u16*)alloc((size_t)(NN + 1) * HD * 2);  // +1 zero row for CSR padding
    u16*   aggb     = (u16*)alloc((size_t)NN * HD * 2);        // aliased: bucket buffer pre-loop
    u16*   wt       = (u16*)alloc((size_t)NL * HD * HD * 2);
    u16*   woutt    = (u16*)alloc((size_t)(NL + 1) * NCP * HD * 2);
    float* dinv     = (float*)alloc((size_t)NN * 4);
    int*   offs     = (int*)alloc((size_t)(NBK * NPB) * 4);
    int*   oend     = (int*)alloc((size_t)(NBK * NPB) * 4);
    int*   gcur     = (int*)alloc((size_t)NBK * 4);
    int*   csr_src  = (int*)alloc(((size_t)NBK * PCAP + 256) * 4);
    float* stats    = (float*)alloc((size_t)NL * 2 * HD * 4);

    u32* bb = (u32*)aggb; // 196*9216*4 = 7.2 MB <= 25.6 MB; dead before layer loop

    k_conv_w<<<(NL * HD * HD + 255) / 256, 256, 0, stream>>>(Ws, wt, gcur, stats,
                                                             hw + (size_t)NN * HD,
                                                             W_out, woutt);
    k_bin<<<NBINBLK, 256, 0, stream>>>(src, dst, gcur, bb);
    k_csr<<<NBK, 512, 0, stream>>>(gcur, bb, csr_src, offs, oend, dinv);

    k_convgemm<<<(NN + 63) / 64, 256, 0, stream>>>(x, wt, woutt, b_out, dinv, hw, out);

    for (int l = 0; l < NL; l++){
        k_agg<<<(NN + 63) / 64, 256, 0, stream>>>(hw, offs, oend, csr_src, dinv,
                                                  bs + (size_t)l * HD, aggb,
                                                  stats + (size_t)l * 2 * HD);
        if (l < NL - 1){
            k_gemmbn<true><<<(NN + 63) / 64, 256, 0, stream>>>(
                aggb, stats + (size_t)l * 2 * HD, gammas + (size_t)l * HD,
                betas + (size_t)l * HD, wt + (size_t)(l + 1) * HD * HD,
                woutt + (size_t)(l + 1) * NCP * HD, dinv, hw, out);
        } else {
            k_gemmbn<false><<<(NN + 63) / 64, 256, 0, stream>>>(
                aggb, stats + (size_t)l * 2 * HD, gammas + (size_t)l * HD,
                betas + (size_t)l * HD, nullptr,
                woutt + (size_t)(l + 1) * NCP * HD, dinv, nullptr, out);
        }
    }
}

// Round 12
// 392.870 us; speedup vs baseline: 2.2996x; 1.0706x over previous
//
#include <hip/hip_runtime.h>

#define NN 100000
#define NE 1600000
#define HD 128
#define NL 3
#define NC 40
#define NCP 48      // padded head cols (multiple of 16)

#define NBK 196     // dst buckets (512 nodes each; 196*512 = 100352 >= NN)
#define NPB 512     // nodes per bucket
#define BSH 9       // bucket shift (dst >> 9)
#define CAP 9216    // per-bucket raw edge capacity (mean 8163, +11 sigma)
#define PCAP 13312  // per-bucket padded CSR capacity
#define EPB 6400    // edges per bin block
#define NBINBLK 250 // 250 * 6400 = NE

typedef unsigned int u32;
typedef unsigned short u16;
typedef signed char i8;
typedef __attribute__((ext_vector_type(8))) short short8;
typedef __attribute__((ext_vector_type(4))) float f32x4;

__device__ __forceinline__ float b2f(u16 h){
    union{u32 u; float f;} v; v.u = ((u32)h) << 16; return v.f;
}
__device__ __forceinline__ u16 f2b(float f){
    union{float f; u32 u;} v; v.f = f;
    u32 u = v.u;
    u32 r = (u + 0x7FFFu + ((u >> 16) & 1u)) >> 16;
    return (u16)r;
}

// ---------------- weight conversion + zero-inits ----------------
__global__ void k_conv_w(const float* __restrict__ Ws, u16* __restrict__ wt,
                         int* __restrict__ gcur, float* __restrict__ stats,
                         u32* __restrict__ hw8zero, float* __restrict__ invscale,
                         const float* __restrict__ Wout, u16* __restrict__ woutt){
    int i = blockIdx.x * blockDim.x + threadIdx.x;
    if (i < NBK) gcur[i] = 0;
    if (i < NL * 2 * HD) stats[i] = 0.f;
    if (i < 32) hw8zero[i] = 0;          // zero row NN of hw8 (128 B)
    if (i == 0) invscale[NN] = 0.f;
    if (i < (NL + 1) * NCP * HD){
        int li = i / (NCP * HD);
        int r = i % (NCP * HD);
        int n = r / HD;
        int k = r % HD;
        woutt[i] = (n < NC) ? f2b(Wout[(size_t)(li * HD + k) * NC + n]) : (u16)0;
    }
    if (i >= NL * HD * HD) return;
    int l = i / (HD * HD);
    int r = i % (HD * HD);
    int n = r / HD;
    int k = r % HD;
    wt[i] = f2b(Ws[l * HD * HD + k * HD + n]);
}

// ---------------- pass 1: bin edges by dst bucket; packed u32 (src | (d&511)<<17) ----------------
__launch_bounds__(256)
__global__ void k_bin(const int* __restrict__ src, const int* __restrict__ dst,
                      int* __restrict__ gcur, u32* __restrict__ bb){
    __shared__ int hist[NBK];
    __shared__ int lbase[NBK];
    __shared__ int gbase[NBK];
    __shared__ int cur[NBK];
    __shared__ int wsum[4];
    __shared__ uint2 stage[EPB]; // 51.2 KB
    int tid = threadIdx.x;
    int e0 = blockIdx.x * EPB;
    for (int i = tid; i < NBK; i += 256) hist[i] = 0;
    __syncthreads();
    for (int k = tid; k < EPB; k += 256){
        int d = dst[e0 + k];
        atomicAdd(&hist[d >> BSH], 1);
    }
    __syncthreads();
    {
        int v = (tid < NBK) ? hist[tid] : 0;
        int lane = tid & 63, w = tid >> 6;
        int incl = v;
        #pragma unroll
        for (int dlt = 1; dlt < 64; dlt <<= 1){
            int t = __shfl_up(incl, dlt);
            if (lane >= dlt) incl += t;
        }
        if (lane == 63) wsum[w] = incl;
        __syncthreads();
        if (tid == 0){
            int run = 0;
            #pragma unroll
            for (int j = 0; j < 4; j++){ int t = wsum[j]; wsum[j] = run; run += t; }
        }
        __syncthreads();
        int excl = wsum[w] + incl - v;
        if (tid < NBK){ lbase[tid] = excl; cur[tid] = excl; }
    }
    __syncthreads();
    if (tid < NBK) gbase[tid] = atomicAdd(&gcur[tid], hist[tid]);
    __syncthreads();
    for (int k = tid; k < EPB; k += 256){
        int s = src[e0 + k], d = dst[e0 + k];
        int pos = atomicAdd(&cur[d >> BSH], 1);
        stage[pos] = make_uint2((u32)s, (u32)d);
    }
    __syncthreads();
    for (int k = tid; k < EPB; k += 256){
        uint2 sd = stage[k];
        int b = (int)(sd.y >> BSH);
        int g = gbase[b] + (k - lbase[b]);
        if (g < CAP) bb[(size_t)b * CAP + g] = sd.x | ((sd.y & (NPB - 1)) << 17);
    }
}

// ---------------- pass 2: per-bucket padded CSR build ----------------
__launch_bounds__(512)
__global__ void k_csr(const int* __restrict__ gcur, const u32* __restrict__ bb,
                      int* __restrict__ csr_src, int* __restrict__ offs,
                      int* __restrict__ oend, float* __restrict__ dinv){
    __shared__ int hist[NPB];
    __shared__ int cur[NPB];
    __shared__ int wsum[8];
    __shared__ int totp_s;
    __shared__ int lcsr[PCAP]; // 52 KB
    int tid = threadIdx.x;
    int b = blockIdx.x;
    int cnt_b = gcur[b]; if (cnt_b > CAP) cnt_b = CAP;
    const u32* eb = bb + (size_t)b * CAP;
    hist[tid] = 0;
    __syncthreads();
    for (int k = tid; k < cnt_b; k += 512)
        atomicAdd(&hist[eb[k] >> 17], 1);
    __syncthreads();
    int cnt = hist[tid];
    int ps = (1 + cnt + 7) & ~7;   // padded slots incl self
    int lane = tid & 63, w = tid >> 6;
    int incl = ps;
    #pragma unroll
    for (int dlt = 1; dlt < 64; dlt <<= 1){
        int t = __shfl_up(incl, dlt);
        if (lane >= dlt) incl += t;
    }
    if (lane == 63) wsum[w] = incl;
    __syncthreads();
    if (tid == 0){
        int run = 0;
        #pragma unroll
        for (int j = 0; j < 8; j++){ int t = wsum[j]; wsum[j] = run; run += t; }
        totp_s = run;
    }
    __syncthreads();
    int excl = wsum[w] + incl - ps;
    int n = b * NPB + tid;
    offs[n] = b * PCAP + excl;
    oend[n] = b * PCAP + excl + ps;
    if (n < NN) dinv[n] = rsqrtf((float)(cnt + 1));
    cur[tid] = excl + 1;
    int totp = totp_s;
    __syncthreads();
    for (int k = tid; k < totp; k += 512) lcsr[k] = NN;   // pad -> zero row
    __syncthreads();
    lcsr[excl] = (n < NN) ? n : NN;
    __syncthreads();
    for (int k = tid; k < cnt_b; k += 512){
        u32 sd = eb[k];
        int pos = atomicAdd(&cur[sd >> 17], 1);
        lcsr[pos] = (int)(sd & 0x1FFFFu);
    }
    __syncthreads();
    for (int k = tid; k < totp; k += 512)
        csr_src[b * PCAP + k] = lcsr[k];
}

// int8 row-quantized epilogue helper: writes hw8 row bytes + invscale
#define EPI_INT8(ACC, DVR, RR) { \
    float m_ = 0.f; \
    _Pragma("unroll") \
    for (int ct_ = 0; ct_ < 8; ct_++) m_ = fmaxf(m_, fabsf(ACC[ct_][RR##_r])); \
    _Pragma("unroll") \
    for (int off_ = 1; off_ < 16; off_ <<= 1) m_ = fmaxf(m_, __shfl_xor(m_, off_)); \
    float s_ = (m_ > 0.f) ? 127.0f / m_ : 0.f; \
    if (RR < NN){ \
        _Pragma("unroll") \
        for (int ct_ = 0; ct_ < 8; ct_++){ \
            int q_ = (int)rintf(ACC[ct_][RR##_r] * s_); \
            hw8[(size_t)RR * HD + ct_ * 16 + dcol] = (i8)q_; \
        } \
        if (dcol == 0) invscale[RR] = m_ * DVR * (1.0f / 127.0f); \
    } }

// ---------------- fused x->bf16 + layer0 GEMM + head slice 0 (MFMA) ----------------
__launch_bounds__(256)
__global__ void k_convgemm(const float* __restrict__ x, const u16* __restrict__ wt,
                           const u16* __restrict__ woutt, const float* __restrict__ bout,
                           const float* __restrict__ dinv, i8* __restrict__ hw8,
                           float* __restrict__ invscale, float* __restrict__ out){
    __shared__ u16 wlds[HD * HD];   // 32 KB
    __shared__ u16 wolds[NCP * HD]; // 12 KB
    __shared__ float bl[NC];
    int tid = threadIdx.x;
    {
        const uint4* g = reinterpret_cast<const uint4*>(wt);
        #pragma unroll
        for (int i = 0; i < 8; i++){
            int lin16 = tid + 256 * i;
            uint4 v = g[lin16];
            int c = lin16 >> 4;
            int addr16 = lin16 ^ (c & 7);
            reinterpret_cast<uint4*>(wlds)[addr16] = v;
        }
    }
    {
        const uint4* g = reinterpret_cast<const uint4*>(woutt);
        #pragma unroll
        for (int i = 0; i < 3; i++){
            int lin16 = tid + 256 * i;
            uint4 v = g[lin16];
            int c = lin16 >> 4;
            int addr16 = lin16 ^ (c & 7);
            reinterpret_cast<uint4*>(wolds)[addr16] = v;
        }
    }
    if (tid < NC) bl[tid] = bout[tid];
    __syncthreads();

    int wv = tid >> 6, lane = tid & 63;
    int row_base = blockIdx.x * 64 + wv * 16;
    int arow = row_base + (lane & 15);
    if (arow >= NN) arow = NN - 1;
    int koff = (lane >> 4) * 8;

    f32x4 accW[8];
    f32x4 accH[3];
    #pragma unroll
    for (int t = 0; t < 8; t++) accW[t] = (f32x4){0.f, 0.f, 0.f, 0.f};
    #pragma unroll
    for (int t = 0; t < 3; t++) accH[t] = (f32x4){0.f, 0.f, 0.f, 0.f};

    #pragma unroll
    for (int kk = 0; kk < 4; kk++){
        int fb = kk * 32 + koff;
        const float4* xr = reinterpret_cast<const float4*>(x + (size_t)arow * HD + fb);
        float4 v0 = xr[0];
        float4 v1 = xr[1];
        short8 a;
        a[0] = (short)f2b(v0.x); a[1] = (short)f2b(v0.y);
        a[2] = (short)f2b(v0.z); a[3] = (short)f2b(v0.w);
        a[4] = (short)f2b(v1.x); a[5] = (short)f2b(v1.y);
        a[6] = (short)f2b(v1.z); a[7] = (short)f2b(v1.w);
        #pragma unroll
        for (int ct = 0; ct < 8; ct++){
            int c = ct * 16 + (lane & 15);
            int addr16 = (c * 16 + kk * 4 + (koff >> 3)) ^ (c & 7);
            short8 b = *reinterpret_cast<const short8*>(wlds + addr16 * 8);
            accW[ct] = __builtin_amdgcn_mfma_f32_16x16x32_bf16(a, b, accW[ct], 0, 0, 0);
        }
        #pragma unroll
        for (int ht = 0; ht < 3; ht++){
            int c = ht * 16 + (lane & 15);
            int addr16 = (c * 16 + kk * 4 + (koff >> 3)) ^ (c & 7);
            short8 b = *reinterpret_cast<const short8*>(wolds + addr16 * 8);
            accH[ht] = __builtin_amdgcn_mfma_f32_16x16x32_bf16(a, b, accH[ht], 0, 0, 0);
        }
    }

    int drow = row_base + (lane >> 4) * 4;
    int dcol = lane & 15;
    #pragma unroll
    for (int rr_r = 0; rr_r < 4; rr_r++){
        int rr = drow + rr_r;
        float dvr = dinv[rr < NN ? rr : NN - 1];
        EPI_INT8(accW, dvr, rr)
    }
    #pragma unroll
    for (int ht = 0; ht < 3; ht++){
        int col = ht * 16 + dcol;
        if (col < NC){
            float bv = bl[col];
            #pragma unroll
            for (int r = 0; r < 4; r++){
                int rr = drow + r;
                if (rr < NN) out[(size_t)rr * NC + col] = bv + accH[ht][r];
            }
        }
    }
}

// ---------------- fused BN(from sums) + layer-GEMM + head-GEMM (MFMA) ----------------
template<bool DO_HW>
__launch_bounds__(256)
__global__ void k_gemmbn(const u16* __restrict__ agg, const float* __restrict__ sums,
                         const float* __restrict__ gamma, const float* __restrict__ beta,
                         const u16* __restrict__ wt, const u16* __restrict__ woutt,
                         const float* __restrict__ dinv, i8* __restrict__ hw8,
                         float* __restrict__ invscale, float* __restrict__ out){
    __shared__ u16 wlds[HD * HD];   // 32 KB
    __shared__ u16 wolds[NCP * HD]; // 12 KB
    __shared__ float Al[HD];
    __shared__ float Cl[HD];
    int tid = threadIdx.x;
    if (DO_HW){
        const uint4* g = reinterpret_cast<const uint4*>(wt);
        #pragma unroll
        for (int i = 0; i < 8; i++){
            int lin16 = tid + 256 * i;
            uint4 v = g[lin16];
            int c = lin16 >> 4;
            int addr16 = lin16 ^ (c & 7);
            reinterpret_cast<uint4*>(wlds)[addr16] = v;
        }
    }
    {
        const uint4* g = reinterpret_cast<const uint4*>(woutt);
        #pragma unroll
        for (int i = 0; i < 3; i++){
            int lin16 = tid + 256 * i;
            uint4 v = g[lin16];
            int c = lin16 >> 4;
            int addr16 = lin16 ^ (c & 7);
            reinterpret_cast<uint4*>(wolds)[addr16] = v;
        }
    }
    if (tid < HD){
        float mu = sums[tid] / (float)NN;
        float var = sums[HD + tid] / (float)NN - mu * mu;
        float inv = rsqrtf(var + 1e-5f);
        float a = gamma[tid] * inv;
        Al[tid] = a;
        Cl[tid] = beta[tid] - mu * a;
    }
    __syncthreads();

    int wv = tid >> 6, lane = tid & 63;
    int row_base = blockIdx.x * 64 + wv * 16;
    int arow = row_base + (lane & 15);
    if (arow >= NN) arow = NN - 1;
    int koff = (lane >> 4) * 8;

    f32x4 accW[8];
    f32x4 accH[3];
    #pragma unroll
    for (int t = 0; t < 8; t++) accW[t] = (f32x4){0.f, 0.f, 0.f, 0.f};
    #pragma unroll
    for (int t = 0; t < 3; t++) accH[t] = (f32x4){0.f, 0.f, 0.f, 0.f};

    #pragma unroll
    for (int kk = 0; kk < 4; kk++){
        int fb = kk * 32 + koff;
        short8 raw = *reinterpret_cast<const short8*>(agg + (size_t)arow * HD + fb);
        f32x4 A0 = *reinterpret_cast<const f32x4*>(&Al[fb]);
        f32x4 A1 = *reinterpret_cast<const f32x4*>(&Al[fb + 4]);
        f32x4 C0 = *reinterpret_cast<const f32x4*>(&Cl[fb]);
        f32x4 C1 = *reinterpret_cast<const f32x4*>(&Cl[fb + 4]);
        short8 a;
        #pragma unroll
        for (int j = 0; j < 4; j++){
            a[j]     = (short)f2b(b2f((u16)raw[j])     * A0[j] + C0[j]);
            a[j + 4] = (short)f2b(b2f((u16)raw[j + 4]) * A1[j] + C1[j]);
        }
        if (DO_HW){
            #pragma unroll
            for (int ct = 0; ct < 8; ct++){
                int c = ct * 16 + (lane & 15);
                int addr16 = (c * 16 + kk * 4 + (koff >> 3)) ^ (c & 7);
                short8 b = *reinterpret_cast<const short8*>(wlds + addr16 * 8);
                accW[ct] = __builtin_amdgcn_mfma_f32_16x16x32_bf16(a, b, accW[ct], 0, 0, 0);
            }
        }
        #pragma unroll
        for (int ht = 0; ht < 3; ht++){
            int c = ht * 16 + (lane & 15);
            int addr16 = (c * 16 + kk * 4 + (koff >> 3)) ^ (c & 7);
            short8 b = *reinterpret_cast<const short8*>(wolds + addr16 * 8);
            accH[ht] = __builtin_amdgcn_mfma_f32_16x16x32_bf16(a, b, accH[ht], 0, 0, 0);
        }
    }

    int drow = row_base + (lane >> 4) * 4;
    int dcol = lane & 15;
    if (DO_HW){
        #pragma unroll
        for (int rr_r = 0; rr_r < 4; rr_r++){
            int rr = drow + rr_r;
            float dvr = dinv[rr < NN ? rr : NN - 1];
            EPI_INT8(accW, dvr, rr)
        }
    }
    #pragma unroll
    for (int ht = 0; ht < 3; ht++){
        int col = ht * 16 + dcol;
        if (col < NC){
            #pragma unroll
            for (int r = 0; r < 4; r++){
                int rr = drow + r;
                if (rr < NN) out[(size_t)rr * NC + col] += accH[ht][r];
            }
        }
    }
}

// ---------------- aggregation + BN stats (int8 gather, per-row scale) ----------------
#define G8(bufv, bufs, c) { _Pragma("unroll") \
    for (int j = 0; j < 8; j++){ \
        u32 uid = (u32)__builtin_amdgcn_readlane(idxv, (c) * 8 + j); \
        bufs[j] = __int_as_float(__builtin_amdgcn_readlane(scv, (c) * 8 + j)); \
        bufv[j] = (u32)hw16[(size_t)uid * 64 + (u32)lane]; } }

#define A8(bufv, bufs, x0, x1) { _Pragma("unroll") \
    for (int j = 0; j < 8; j++){ \
        int q0 = (int)(i8)(bufv[j] & 0xFF); \
        int q1 = (int)(i8)(bufv[j] >> 8); \
        x0 += (float)q0 * bufs[j]; x1 += (float)q1 * bufs[j]; } }

__launch_bounds__(256)
__global__ void k_agg(const i8* __restrict__ hw8, const float* __restrict__ invscale,
                      const int* __restrict__ offs, const int* __restrict__ oend,
                      const int* __restrict__ csr_src, const float* __restrict__ dinv,
                      const float* __restrict__ bias, u16* __restrict__ agg,
                      float* __restrict__ sums){
    __shared__ float redS[4][HD];
    __shared__ float redQ[4][HD];
    int tid = threadIdx.x;
    int lane = tid & 63;
    int wv = tid >> 6;
    int f0 = lane * 2;
    float b0 = bias[f0], b1 = bias[f0 + 1];
    float s0 = 0.f, s1 = 0.f, q0 = 0.f, q1 = 0.f;
    int n0 = (blockIdx.x * 4 + wv) * 16;
    const u16* hw16 = reinterpret_cast<const u16*>(hw8); // row = 64 u16, lane offset = lane

    for (int k = 0; k < 16; k++){
        int n = n0 + k;
        if (n >= NN) break;
        float a0 = 0.f, a1 = 0.f, c0 = 0.f, c1 = 0.f;
        int e = offs[n], e1 = oend[n];
        int rem = e1 - e;
        while (rem > 0){
            int win = rem < 64 ? rem : 64;
            int idxv = csr_src[e + lane];       // coalesced index stage
            idxv = min(max(idxv, 0), NN);       // clamp (poison-gap lanes safe)
            int scv = __float_as_int(invscale[idxv]);  // per-row scales, L2-resident
            int nch = win >> 3;
            u32 va[8], vb[8];
            float sa[8], sb[8];

            G8(va, sa, 0)
            for (int c = 1; c < nch; c++){
                if (c & 1){
                    G8(vb, sb, c)
                    A8(va, sa, a0, a1)
                } else {
                    G8(va, sa, c)
                    A8(vb, sb, c0, c1)
                }
            }
            if (nch & 1){
                A8(va, sa, a0, a1)
            } else {
                A8(vb, sb, c0, c1)
            }
            e += win; rem -= win;
        }
        float di = dinv[n];
        a0 = (a0 + c0) * di + b0;
        a1 = (a1 + c1) * di + b1;
        u32 o = ((u32)f2b(a1) << 16) | (u32)f2b(a0);
        *reinterpret_cast<u32*>(agg + (size_t)n * HD + f0) = o;
        s0 += a0; s1 += a1; q0 += a0 * a0; q1 += a1 * a1;
    }

    redS[wv][f0] = s0; redS[wv][f0 + 1] = s1;
    redQ[wv][f0] = q0; redQ[wv][f0 + 1] = q1;
    __syncthreads();
    if (tid < HD){
        float ts = redS[0][tid] + redS[1][tid] + redS[2][tid] + redS[3][tid];
        float tq = redQ[0][tid] + redQ[1][tid] + redQ[2][tid] + redQ[3][tid];
        atomicAdd(&sums[tid], ts);
        atomicAdd(&sums[HD + tid], tq);
    }
}

// ---------------- launch ----------------
extern "C" void kernel_launch(void* const* d_in, const int* in_sizes, int n_in,
                              void* d_out, int out_size, void* d_ws, size_t ws_size,
                              hipStream_t stream){
    const float* x      = (const float*)d_in[0];
    const float* Ws     = (const float*)d_in[1];
    const float* bs     = (const float*)d_in[2];
    const float* gammas = (const float*)d_in[3];
    const float* betas  = (const float*)d_in[4];
    const float* W_out  = (const float*)d_in[5];
    const float* b_out  = (const float*)d_in[6];
    const int*   ei     = (const int*)d_in[7];
    const int* src = ei;
    const int* dst = ei + NE;
    float* out = (float*)d_out;

    char* ws = (char*)d_ws;
    size_t off = 0;
    auto alloc = [&](size_t bytes) -> char* {
        char* p = ws + off;
        off += (bytes + 255) & ~(size_t)255;
        return p;
    };
    i8*    hw8      = (i8*)alloc((size_t)(NN + 1) * HD);       // int8 rows (+ zero row NN)
    float* invscale = (float*)alloc((size_t)(NN + 1) * 4);
    u16*   aggb     = (u16*)alloc((size_t)NN * HD * 2);        // aliased: bucket buffer pre-loop
    u16*   wt       = (u16*)alloc((size_t)NL * HD * HD * 2);
    u16*   woutt    = (u16*)alloc((size_t)(NL + 1) * NCP * HD * 2);
    float* dinv     = (float*)alloc((size_t)NN * 4);
    int*   offs     = (int*)alloc((size_t)(NBK * NPB) * 4);
    int*   oend     = (int*)alloc((size_t)(NBK * NPB) * 4);
    int*   gcur     = (int*)alloc((size_t)NBK * 4);
    int*   csr_src  = (int*)alloc(((size_t)NBK * PCAP + 256) * 4);
    float* stats    = (float*)alloc((size_t)NL * 2 * HD * 4);

    u32* bb = (u32*)aggb; // 196*9216*4 = 7.2 MB <= 25.6 MB; dead before layer loop

    k_conv_w<<<(NL * HD * HD + 255) / 256, 256, 0, stream>>>(
        Ws, wt, gcur, stats, (u32*)(hw8 + (size_t)NN * HD), invscale, W_out, woutt);
    k_bin<<<NBINBLK, 256, 0, stream>>>(src, dst, gcur, bb);
    k_csr<<<NBK, 512, 0, stream>>>(gcur, bb, csr_src, offs, oend, dinv);

    k_convgemm<<<(NN + 63) / 64, 256, 0, stream>>>(x, wt, woutt, b_out, dinv,
                                                   hw8, invscale, out);

    for (int l = 0; l < NL; l++){
        k_agg<<<(NN + 63) / 64, 256, 0, stream>>>(hw8, invscale, offs, oend, csr_src,
                                                  dinv, bs + (size_t)l * HD, aggb,
                                                  stats + (size_t)l * 2 * HD);
        if (l < NL - 1){
            k_gemmbn<true><<<(NN + 63) / 64, 256, 0, stream>>>(
                aggb, stats + (size_t)l * 2 * HD, gammas + (size_t)l * HD,
                betas + (size_t)l * HD, wt + (size_t)(l + 1) * HD * HD,
                woutt + (size_t)(l + 1) * NCP * HD, dinv, hw8, invscale, out);
        } else {
            k_gemmbn<false><<<(NN + 63) / 64, 256, 0, stream>>>(
                aggb, stats + (size_t)l * 2 * HD, gammas + (size_t)l * HD,
                betas + (size_t)l * HD, nullptr,
                woutt + (size_t)(l + 1) * NCP * HD, dinv, nullptr, invscale, out);
        }
    }
}